// Round 1
// baseline (1332.749 us; speedup 1.0000x reference)
//
#include <hip/hip_runtime.h>
#include <math.h>

#define N_NODES 50000
#define N_EDGES 400000
#define N_GRAPHS 16
#define HEADS 4
#define DHEAD 64
#define NEG_SLOPE 0.2f

// ---------------- h0 = feat @ W_in + b_in  [N,64] ----------------
__global__ __launch_bounds__(256) void k_h0(const float* __restrict__ feat,
                                            const float* __restrict__ W_in,
                                            const float* __restrict__ b_in,
                                            float* __restrict__ h0, int n) {
    int idx = blockIdx.x * 256 + threadIdx.x;
    if (idx >= n * 64) return;
    int node = idx >> 6, d = idx & 63;
    float acc = b_in[d];
    #pragma unroll
    for (int k = 0; k < 16; k++) acc += feat[node * 16 + k] * W_in[k * 64 + d];
    h0[idx] = acc;
}

// ---------------- CSR build ----------------
__global__ __launch_bounds__(256) void k_zero_int(int* __restrict__ p, int n) {
    int i = blockIdx.x * 256 + threadIdx.x;
    if (i < n) p[i] = 0;
}
__global__ __launch_bounds__(256) void k_zero_f(float* __restrict__ p, int n) {
    int i = blockIdx.x * 256 + threadIdx.x;
    if (i < n) p[i] = 0.f;
}
__global__ __launch_bounds__(256) void k_hist(const int* __restrict__ dst, int* __restrict__ indeg, int e) {
    int i = blockIdx.x * 256 + threadIdx.x;
    if (i < e) atomicAdd(&indeg[dst[i]], 1);
}
// single-block exclusive scan over N entries -> offsets[0..N]
__global__ __launch_bounds__(1024) void k_scan(const int* __restrict__ indeg, int* __restrict__ offsets, int n) {
    __shared__ int tmp[1024];
    __shared__ int s_running;
    int t = threadIdx.x;
    if (t == 0) s_running = 0;
    __syncthreads();
    for (int base = 0; base < n; base += 1024) {
        int v = (base + t < n) ? indeg[base + t] : 0;
        tmp[t] = v;
        __syncthreads();
        for (int off = 1; off < 1024; off <<= 1) {
            int add = (t >= off) ? tmp[t - off] : 0;
            __syncthreads();
            tmp[t] += add;
            __syncthreads();
        }
        int incl = tmp[t];
        int run = s_running;
        if (base + t < n) offsets[base + t] = run + incl - v;
        __syncthreads();
        if (t == 1023) s_running = run + incl;
        __syncthreads();
    }
    if (t == 0) offsets[n] = s_running;
}
__global__ __launch_bounds__(256) void k_fill(const int* __restrict__ src, const int* __restrict__ dst,
                                              const int* __restrict__ offsets, int* __restrict__ cursor,
                                              int* __restrict__ csr_src, int e) {
    int i = blockIdx.x * 256 + threadIdx.x;
    if (i >= e) return;
    int d = dst[i];
    int slot = offsets[d] + atomicAdd(&cursor[d], 1);
    csr_src[slot] = src[i];
}

// ---------------- fs/fd = [h|h0] @ W + b   [N,256] ----------------
// grid: (ceil(N/32), 2); block 256. blockIdx.y: 0 -> (W_src,fs), 1 -> (W_dst,fd)
__global__ __launch_bounds__(256) void k_gemm(const float* __restrict__ hcur, const float* __restrict__ h0,
                                              const float* __restrict__ Wsrc, const float* __restrict__ bsrc,
                                              const float* __restrict__ Wdst, const float* __restrict__ bdst,
                                              float* __restrict__ fs, float* __restrict__ fd, int n) {
    const float* __restrict__ W = (blockIdx.y == 0) ? Wsrc : Wdst;
    const float* __restrict__ bias = (blockIdx.y == 0) ? bsrc : bdst;
    float* __restrict__ out = (blockIdx.y == 0) ? fs : fd;
    __shared__ float xs[32][128];
    int n0 = blockIdx.x * 32;
    int t = threadIdx.x;
    for (int i = t; i < 32 * 128; i += 256) {
        int r = i >> 7, k = i & 127;
        int node = n0 + r;
        float v = 0.f;
        if (node < n) v = (k < 64) ? hcur[node * 64 + k] : h0[node * 64 + (k - 64)];
        xs[r][k] = v;
    }
    __syncthreads();
    int col = t;  // 256 threads <-> 256 cols
    float acc[32];
    float bb = bias[col];
    #pragma unroll
    for (int r = 0; r < 32; r++) acc[r] = bb;
    for (int k = 0; k < 128; k += 4) {
        float w0 = W[(k + 0) * 256 + col];
        float w1 = W[(k + 1) * 256 + col];
        float w2 = W[(k + 2) * 256 + col];
        float w3 = W[(k + 3) * 256 + col];
        #pragma unroll
        for (int r = 0; r < 32; r++) {
            float4 xv = *(const float4*)&xs[r][k];
            acc[r] += xv.x * w0 + xv.y * w1 + xv.z * w2 + xv.w * w3;
        }
    }
    for (int r = 0; r < 32; r++) {
        int node = n0 + r;
        if (node < n) out[node * 256 + col] = acc[r];
    }
}

// ---------------- per-node online-softmax aggregation ----------------
// one wave per node; lane = d; 4 heads in registers.
__global__ __launch_bounds__(256) void k_agg(const float* __restrict__ fs, const float* __restrict__ fd,
                                             const int* __restrict__ offsets, const int* __restrict__ csr_src,
                                             const float* __restrict__ attn, float* __restrict__ hout, int n) {
    int wave = threadIdx.x >> 6;
    int lane = threadIdx.x & 63;
    int node = blockIdx.x * 4 + wave;
    if (node >= n) return;
    float at[HEADS], fdv[HEADS], m[HEADS], l[HEADS], acc[HEADS];
    #pragma unroll
    for (int h = 0; h < HEADS; h++) {
        at[h] = attn[h * 64 + lane];
        fdv[h] = fd[node * 256 + h * 64 + lane];
        m[h] = -INFINITY; l[h] = 0.f; acc[h] = 0.f;
    }
    int beg = offsets[node], end = offsets[node + 1];
    for (int j = beg; j < end; j++) {
        int s = csr_src[j];
        float fsv[HEADS], logit[HEADS];
        #pragma unroll
        for (int h = 0; h < HEADS; h++) {
            fsv[h] = fs[s * 256 + h * 64 + lane];
            float e = fsv[h] + fdv[h];
            e = (e > 0.f) ? e : NEG_SLOPE * e;
            float p = at[h] * e;
            #pragma unroll
            for (int off = 32; off > 0; off >>= 1) p += __shfl_xor(p, off, 64);
            logit[h] = p;
        }
        #pragma unroll
        for (int h = 0; h < HEADS; h++) {
            float nm = fmaxf(m[h], logit[h]);
            float scale = __expf(m[h] - nm);
            float w = __expf(logit[h] - nm);
            l[h] = l[h] * scale + w;
            acc[h] = acc[h] * scale + w * fsv[h];
            m[h] = nm;
        }
    }
    float o = 0.f;
    #pragma unroll
    for (int h = 0; h < HEADS; h++) {
        float r = (l[h] > 0.f) ? acc[h] / l[h] : 0.f;
        o += tanhf(r);
    }
    hout[node * 64 + lane] = o;
}

// ---------------- graph readout ----------------
__global__ __launch_bounds__(256) void k_readout(const float* __restrict__ h, const float* __restrict__ is_root,
                                                 const int* __restrict__ gid, float* __restrict__ hg, int n) {
    __shared__ float s_hg[N_GRAPHS * 64];
    int t = threadIdx.x;
    for (int i = t; i < N_GRAPHS * 64; i += 256) s_hg[i] = 0.f;
    __syncthreads();
    int d = t & 63;
    int local = t >> 6;
    int start = blockIdx.x * 1024;
    int stop = min(start + 1024, n);
    for (int i = start + local; i < stop; i += 4) {
        float v = h[i * 64 + d] * is_root[i];
        atomicAdd(&s_hg[gid[i] * 64 + d], v);
    }
    __syncthreads();
    for (int i = t; i < N_GRAPHS * 64; i += 256) atomicAdd(&hg[i], s_hg[i]);
}

__global__ __launch_bounds__(512) void k_out(const float* __restrict__ hg, const float* __restrict__ W_out,
                                             const float* __restrict__ b_out, float* __restrict__ out) {
    int t = threadIdx.x;
    if (t >= N_GRAPHS * 32) return;
    int b = t >> 5, c = t & 31;
    float a = b_out[c];
    #pragma unroll
    for (int d = 0; d < 64; d++) a += hg[b * 64 + d] * W_out[d * 32 + c];
    out[t] = a;
}

extern "C" void kernel_launch(void* const* d_in, const int* in_sizes, int n_in,
                              void* d_out, int out_size, void* d_ws, size_t ws_size,
                              hipStream_t stream) {
    const float* feat   = (const float*)d_in[0];
    const float* is_root= (const float*)d_in[1];
    const int*   src    = (const int*)d_in[2];
    const int*   dst    = (const int*)d_in[3];
    const int*   gid    = (const int*)d_in[4];
    const float* W_in   = (const float*)d_in[5];
    const float* b_in   = (const float*)d_in[6];
    const float* W_src  = (const float*)d_in[7];
    const float* b_src  = (const float*)d_in[8];
    const float* W_dst  = (const float*)d_in[9];
    const float* b_dst  = (const float*)d_in[10];
    const float* attn   = (const float*)d_in[11];
    const float* W_out  = (const float*)d_in[12];
    const float* b_out  = (const float*)d_in[13];
    float* out = (float*)d_out;

    char* ws = (char*)d_ws;
    size_t off = 0;
    auto take = [&](size_t bytes) -> char* {
        char* p = ws + off;
        off = (off + bytes + 255) & ~(size_t)255;
        return p;
    };
    float* fs      = (float*)take((size_t)N_NODES * 256 * 4);
    float* fd      = (float*)take((size_t)N_NODES * 256 * 4);
    float* h0      = (float*)take((size_t)N_NODES * 64 * 4);
    float* hA      = (float*)take((size_t)N_NODES * 64 * 4);
    float* hB      = (float*)take((size_t)N_NODES * 64 * 4);
    float* hg      = (float*)take((size_t)N_GRAPHS * 64 * 4);
    int*   offsets = (int*)take((size_t)(N_NODES + 1) * 4);
    int*   cursor  = (int*)take((size_t)N_NODES * 4);
    int*   csr_src = (int*)take((size_t)N_EDGES * 4);

    const int n = N_NODES, e = N_EDGES;
    dim3 b256(256);

    // h0
    k_h0<<<dim3((n * 64 + 255) / 256), b256, 0, stream>>>(feat, W_in, b_in, h0, n);

    // CSR build (indeg in `cursor` first, then reset cursor for fill)
    k_zero_int<<<dim3((n + 255) / 256), b256, 0, stream>>>(cursor, n);
    k_hist<<<dim3((e + 255) / 256), b256, 0, stream>>>(dst, cursor, e);
    k_scan<<<dim3(1), dim3(1024), 0, stream>>>(cursor, offsets, n);
    k_zero_int<<<dim3((n + 255) / 256), b256, 0, stream>>>(cursor, n);
    k_fill<<<dim3((e + 255) / 256), b256, 0, stream>>>(src, dst, offsets, cursor, csr_src, e);

    // 4 GATv2 layers
    const float* hin = h0;
    float* houts[4] = { hA, hB, hA, hB };
    for (int layer = 0; layer < 4; layer++) {
        k_gemm<<<dim3((n + 31) / 32, 2), b256, 0, stream>>>(hin, h0, W_src, b_src, W_dst, b_dst, fs, fd, n);
        k_agg<<<dim3((n + 3) / 4), b256, 0, stream>>>(fs, fd, offsets, csr_src, attn, houts[layer], n);
        hin = houts[layer];
    }

    // readout
    k_zero_f<<<dim3((N_GRAPHS * 64 + 255) / 256), b256, 0, stream>>>(hg, N_GRAPHS * 64);
    k_readout<<<dim3((n + 1023) / 1024), b256, 0, stream>>>(hB, is_root, gid, hg, n);
    k_out<<<dim3(1), dim3(512), 0, stream>>>(hg, W_out, b_out, out);
}

// Round 2
// 876.811 us; speedup vs baseline: 1.5200x; 1.5200x over previous
//
#include <hip/hip_runtime.h>
#include <math.h>

#define N_NODES 50000
#define N_EDGES 400000
#define N_GRAPHS 16
#define HEADS 4
#define NEG_SLOPE 0.2f

typedef __attribute__((ext_vector_type(8))) short short8;
typedef __attribute__((ext_vector_type(4))) float floatx4;

__device__ __forceinline__ unsigned short f2bf(float x) {
    union { float f; unsigned int u; } v; v.f = x;
    unsigned int r = v.u + 0x7fffu + ((v.u >> 16) & 1u);
    return (unsigned short)(r >> 16);
}
__device__ __forceinline__ float bf2f(unsigned short b) {
    union { unsigned int u; float f; } v; v.u = ((unsigned int)b) << 16;
    return v.f;
}

// ---------------- h0 = feat @ W_in + b_in  [N,64] bf16 ----------------
__global__ __launch_bounds__(256) void k_h0(const float* __restrict__ feat,
                                            const float* __restrict__ W_in,
                                            const float* __restrict__ b_in,
                                            unsigned short* __restrict__ h0, int n) {
    int idx = blockIdx.x * 256 + threadIdx.x;
    if (idx >= n * 64) return;
    int node = idx >> 6, d = idx & 63;
    float acc = b_in[d];
    #pragma unroll
    for (int k = 0; k < 16; k++) acc += feat[node * 16 + k] * W_in[k * 64 + d];
    h0[idx] = f2bf(acc);
}

// ---------------- pack W (fp32 [128,256]) into MFMA B-fragment layout, bf16 ----
// layout: Wpack[mat][ (t*4+q)*64 + lane ][8]  with col=t*16+(lane&15), k=q*32+(lane>>4)*8+j
__global__ __launch_bounds__(256) void k_pack(const float* __restrict__ Wsrc,
                                              const float* __restrict__ Wdst,
                                              unsigned short* __restrict__ Wpack) {
    int idx = blockIdx.x * 256 + threadIdx.x;   // 0 .. 32767
    int mat = blockIdx.y;
    const float* W = mat ? Wdst : Wsrc;
    int j = idx & 7;
    int lane = (idx >> 3) & 63;
    int q = (idx >> 9) & 3;
    int t = (idx >> 11) & 15;
    int col = t * 16 + (lane & 15);
    int k = q * 32 + (lane >> 4) * 8 + j;
    Wpack[mat * 32768 + idx] = f2bf(W[k * 256 + col]);
}

// ---------------- CSR build ----------------
__global__ __launch_bounds__(256) void k_zero_int(int* __restrict__ p, int n) {
    int i = blockIdx.x * 256 + threadIdx.x;
    if (i < n) p[i] = 0;
}
__global__ __launch_bounds__(256) void k_zero_f(float* __restrict__ p, int n) {
    int i = blockIdx.x * 256 + threadIdx.x;
    if (i < n) p[i] = 0.f;
}
__global__ __launch_bounds__(256) void k_hist(const int* __restrict__ dst, int* __restrict__ indeg, int e) {
    int i = blockIdx.x * 256 + threadIdx.x;
    if (i < e) atomicAdd(&indeg[dst[i]], 1);
}
__global__ __launch_bounds__(1024) void k_scan(const int* __restrict__ indeg, int* __restrict__ offsets, int n) {
    __shared__ int tmp[1024];
    __shared__ int s_running;
    int t = threadIdx.x;
    if (t == 0) s_running = 0;
    __syncthreads();
    for (int base = 0; base < n; base += 1024) {
        int v = (base + t < n) ? indeg[base + t] : 0;
        tmp[t] = v;
        __syncthreads();
        for (int off = 1; off < 1024; off <<= 1) {
            int add = (t >= off) ? tmp[t - off] : 0;
            __syncthreads();
            tmp[t] += add;
            __syncthreads();
        }
        int incl = tmp[t];
        int run = s_running;
        if (base + t < n) offsets[base + t] = run + incl - v;
        __syncthreads();
        if (t == 1023) s_running = run + incl;
        __syncthreads();
    }
    if (t == 0) offsets[n] = s_running;
}
__global__ __launch_bounds__(256) void k_fill(const int* __restrict__ src, const int* __restrict__ dst,
                                              const int* __restrict__ offsets, int* __restrict__ cursor,
                                              int* __restrict__ csr_src, int e) {
    int i = blockIdx.x * 256 + threadIdx.x;
    if (i >= e) return;
    int d = dst[i];
    int slot = offsets[d] + atomicAdd(&cursor[d], 1);
    csr_src[slot] = src[i];
}

// ---------------- fs/fd = [h|h0] @ W + b  via MFMA, bf16 out [N,256] ----------------
// block 256 = 4 waves; each wave: 32 rows x 256 cols; grid.x = ceil(n/128), grid.y = 2
__global__ __launch_bounds__(256) void k_gemm(const unsigned short* __restrict__ h,
                                              const unsigned short* __restrict__ h0,
                                              const unsigned short* __restrict__ Wpack,
                                              const float* __restrict__ bsrc,
                                              const float* __restrict__ bdst,
                                              unsigned short* __restrict__ fs,
                                              unsigned short* __restrict__ fd, int n) {
    int mat = blockIdx.y;
    const unsigned short* Wp = Wpack + mat * 32768;
    const float* bias = mat ? bdst : bsrc;
    unsigned short* out = mat ? fd : fs;
    int wave = threadIdx.x >> 6, lane = threadIdx.x & 63;
    int quad = lane >> 4, m16 = lane & 15;
    int row0 = blockIdx.x * 128 + wave * 32;

    floatx4 acc[2][16];
    #pragma unroll
    for (int f = 0; f < 2; f++)
        #pragma unroll
        for (int t = 0; t < 16; t++) acc[f][t] = (floatx4){0.f, 0.f, 0.f, 0.f};

    #pragma unroll
    for (int q = 0; q < 4; q++) {
        int kk = q * 32 + quad * 8;
        short8 a[2];
        #pragma unroll
        for (int f = 0; f < 2; f++) {
            int r = row0 + f * 16 + m16;
            if (r > n - 1) r = n - 1;
            const unsigned short* base = (kk < 64) ? (h + (size_t)r * 64 + kk)
                                                   : (h0 + (size_t)r * 64 + (kk - 64));
            a[f] = *(const short8*)base;
        }
        #pragma unroll
        for (int t = 0; t < 16; t++) {
            short8 b = *(const short8*)(Wp + ((size_t)(t * 4 + q) * 64 + lane) * 8);
            acc[0][t] = __builtin_amdgcn_mfma_f32_16x16x32_bf16(a[0], b, acc[0][t], 0, 0, 0);
            acc[1][t] = __builtin_amdgcn_mfma_f32_16x16x32_bf16(a[1], b, acc[1][t], 0, 0, 0);
        }
    }
    // epilogue: C/D layout col=lane&15, row=quad*4+reg
    #pragma unroll
    for (int f = 0; f < 2; f++) {
        #pragma unroll
        for (int t = 0; t < 16; t++) {
            int col = t * 16 + m16;
            float bb = bias[col];
            #pragma unroll
            for (int r = 0; r < 4; r++) {
                int row = row0 + f * 16 + quad * 4 + r;
                if (row < n) out[(size_t)row * 256 + col] = f2bf(acc[f][t][r] + bb);
            }
        }
    }
}

// ---------------- per-node online-softmax aggregation (bf16 fs/fd) ----------------
// one wave per node. lane = (head = lane>>4, 4 dims dg*4..+3 where dg = lane&15)
__global__ __launch_bounds__(256) void k_agg(const unsigned short* __restrict__ fs,
                                             const unsigned short* __restrict__ fd,
                                             const int* __restrict__ offsets,
                                             const int* __restrict__ csr_src,
                                             const float* __restrict__ attn,
                                             unsigned short* __restrict__ hout, int n) {
    int wave = threadIdx.x >> 6;
    int lane = threadIdx.x & 63;
    int node = blockIdx.x * 4 + wave;
    if (node >= n) return;
    int dg = lane & 15;

    float4 at = *(const float4*)(attn + lane * 4);  // attn[head*64 + dg*4 ..]
    ushort4 fdb = *(const ushort4*)(fd + (size_t)node * 256 + lane * 4);
    float fdv[4] = {bf2f(fdb.x), bf2f(fdb.y), bf2f(fdb.z), bf2f(fdb.w)};
    float atv[4] = {at.x, at.y, at.z, at.w};

    float m = -INFINITY, l = 0.f;
    float acc[4] = {0.f, 0.f, 0.f, 0.f};

    int beg = offsets[node], end = offsets[node + 1];
    for (int j = beg; j < end; j++) {
        int s = csr_src[j];
        ushort4 fsb = *(const ushort4*)(fs + (size_t)s * 256 + lane * 4);
        float fsv[4] = {bf2f(fsb.x), bf2f(fsb.y), bf2f(fsb.z), bf2f(fsb.w)};
        float p = 0.f;
        #pragma unroll
        for (int k = 0; k < 4; k++) {
            float e = fsv[k] + fdv[k];
            e = (e > 0.f) ? e : NEG_SLOPE * e;
            p += atv[k] * e;
        }
        // reduce over the 16 lanes of this head group
        p += __shfl_xor(p, 1, 64);
        p += __shfl_xor(p, 2, 64);
        p += __shfl_xor(p, 4, 64);
        p += __shfl_xor(p, 8, 64);
        float nm = fmaxf(m, p);
        float sc = __expf(m - nm);
        float w = __expf(p - nm);
        l = l * sc + w;
        m = nm;
        #pragma unroll
        for (int k = 0; k < 4; k++) acc[k] = acc[k] * sc + w * fsv[k];
    }
    float o[4];
    float inv = (l > 0.f) ? 1.f / l : 0.f;
    #pragma unroll
    for (int k = 0; k < 4; k++) o[k] = tanhf(acc[k] * inv);
    // sum over heads: lanes l, l^16, l^32, l^48
    #pragma unroll
    for (int k = 0; k < 4; k++) {
        o[k] += __shfl_xor(o[k], 16, 64);
        o[k] += __shfl_xor(o[k], 32, 64);
    }
    if (lane < 16) {
        ushort4 ov = {f2bf(o[0]), f2bf(o[1]), f2bf(o[2]), f2bf(o[3])};
        *(ushort4*)(hout + (size_t)node * 64 + dg * 4) = ov;
    }
}

// ---------------- graph readout ----------------
__global__ __launch_bounds__(256) void k_readout(const unsigned short* __restrict__ h,
                                                 const float* __restrict__ is_root,
                                                 const int* __restrict__ gid, float* __restrict__ hg, int n) {
    __shared__ float s_hg[N_GRAPHS * 64];
    int t = threadIdx.x;
    for (int i = t; i < N_GRAPHS * 64; i += 256) s_hg[i] = 0.f;
    __syncthreads();
    int d = t & 63;
    int local = t >> 6;
    int start = blockIdx.x * 1024;
    int stop = min(start + 1024, n);
    for (int i = start + local; i < stop; i += 4) {
        float v = bf2f(h[(size_t)i * 64 + d]) * is_root[i];
        atomicAdd(&s_hg[gid[i] * 64 + d], v);
    }
    __syncthreads();
    for (int i = t; i < N_GRAPHS * 64; i += 256) atomicAdd(&hg[i], s_hg[i]);
}

__global__ __launch_bounds__(512) void k_out(const float* __restrict__ hg, const float* __restrict__ W_out,
                                             const float* __restrict__ b_out, float* __restrict__ out) {
    int t = threadIdx.x;
    if (t >= N_GRAPHS * 32) return;
    int b = t >> 5, c = t & 31;
    float a = b_out[c];
    #pragma unroll
    for (int d = 0; d < 64; d++) a += hg[b * 64 + d] * W_out[d * 32 + c];
    out[t] = a;
}

extern "C" void kernel_launch(void* const* d_in, const int* in_sizes, int n_in,
                              void* d_out, int out_size, void* d_ws, size_t ws_size,
                              hipStream_t stream) {
    const float* feat    = (const float*)d_in[0];
    const float* is_root = (const float*)d_in[1];
    const int*   src     = (const int*)d_in[2];
    const int*   dst     = (const int*)d_in[3];
    const int*   gid     = (const int*)d_in[4];
    const float* W_in    = (const float*)d_in[5];
    const float* b_in    = (const float*)d_in[6];
    const float* W_src   = (const float*)d_in[7];
    const float* b_src   = (const float*)d_in[8];
    const float* W_dst   = (const float*)d_in[9];
    const float* b_dst   = (const float*)d_in[10];
    const float* attn    = (const float*)d_in[11];
    const float* W_out   = (const float*)d_in[12];
    const float* b_out   = (const float*)d_in[13];
    float* out = (float*)d_out;

    char* ws = (char*)d_ws;
    size_t off = 0;
    auto take = [&](size_t bytes) -> char* {
        char* p = ws + off;
        off = (off + bytes + 255) & ~(size_t)255;
        return p;
    };
    unsigned short* fs    = (unsigned short*)take((size_t)N_NODES * 256 * 2);
    unsigned short* fd    = (unsigned short*)take((size_t)N_NODES * 256 * 2);
    unsigned short* h0    = (unsigned short*)take((size_t)N_NODES * 64 * 2);
    unsigned short* hA    = (unsigned short*)take((size_t)N_NODES * 64 * 2);
    unsigned short* hB    = (unsigned short*)take((size_t)N_NODES * 64 * 2);
    unsigned short* Wpack = (unsigned short*)take((size_t)2 * 32768 * 2);
    float* hg             = (float*)take((size_t)N_GRAPHS * 64 * 4);
    int*   offsets        = (int*)take((size_t)(N_NODES + 1) * 4);
    int*   cursor         = (int*)take((size_t)N_NODES * 4);
    int*   csr_src        = (int*)take((size_t)N_EDGES * 4);

    const int n = N_NODES, e = N_EDGES;
    dim3 b256(256);

    // h0 (bf16) + weight packing
    k_h0<<<dim3((n * 64 + 255) / 256), b256, 0, stream>>>(feat, W_in, b_in, h0, n);
    k_pack<<<dim3(128, 2), b256, 0, stream>>>(W_src, W_dst, Wpack);

    // CSR build
    k_zero_int<<<dim3((n + 255) / 256), b256, 0, stream>>>(cursor, n);
    k_hist<<<dim3((e + 255) / 256), b256, 0, stream>>>(dst, cursor, e);
    k_scan<<<dim3(1), dim3(1024), 0, stream>>>(cursor, offsets, n);
    k_zero_int<<<dim3((n + 255) / 256), b256, 0, stream>>>(cursor, n);
    k_fill<<<dim3((e + 255) / 256), b256, 0, stream>>>(src, dst, offsets, cursor, csr_src, e);

    // 4 GATv2 layers
    const unsigned short* hin = h0;
    unsigned short* houts[4] = { hA, hB, hA, hB };
    for (int layer = 0; layer < 4; layer++) {
        k_gemm<<<dim3((n + 127) / 128, 2), b256, 0, stream>>>(hin, h0, Wpack, b_src, b_dst, fs, fd, n);
        k_agg<<<dim3((n + 3) / 4), b256, 0, stream>>>(fs, fd, offsets, csr_src, attn, houts[layer], n);
        hin = houts[layer];
    }

    // readout
    k_zero_f<<<dim3((N_GRAPHS * 64 + 255) / 256), b256, 0, stream>>>(hg, N_GRAPHS * 64);
    k_readout<<<dim3((n + 1023) / 1024), b256, 0, stream>>>(hB, is_root, gid, hg, n);
    k_out<<<dim3(1), dim3(512), 0, stream>>>(hg, W_out, b_out, out);
}

// Round 3
// 722.034 us; speedup vs baseline: 1.8458x; 1.2144x over previous
//
#include <hip/hip_runtime.h>
#include <math.h>

#define N_NODES 50000
#define N_EDGES 400000
#define N_GRAPHS 16
#define HEADS 4
#define NEG_SLOPE 0.2f

typedef __attribute__((ext_vector_type(8))) short short8;
typedef __attribute__((ext_vector_type(4))) float floatx4;

__device__ __forceinline__ unsigned short f2bf(float x) {
    union { float f; unsigned int u; } v; v.f = x;
    unsigned int r = v.u + 0x7fffu + ((v.u >> 16) & 1u);
    return (unsigned short)(r >> 16);
}
__device__ __forceinline__ float bf2f(unsigned short b) {
    union { unsigned int u; float f; } v; v.u = ((unsigned int)b) << 16;
    return v.f;
}

// ---------------- init: zero cursor + hg ----------------
__global__ __launch_bounds__(256) void k_init(int* __restrict__ cursor, float* __restrict__ hg) {
    int i = blockIdx.x * 256 + threadIdx.x;
    if (i < N_NODES) cursor[i] = 0;
    if (i < N_GRAPHS * 64) hg[i] = 0.f;
}

// ---------------- fused h0 + weight pack ----------------
// blocks [0,12500): h0 = feat @ W_in + b_in (bf16). blocks [12500,12756): pack W.
// Wpack layout: [mat][ (t*4+q)*64 + lane ][8], col=t*16+(lane&15), k=q*32+(lane>>4)*8+j
__global__ __launch_bounds__(256) void k_h0_pack(const float* __restrict__ feat,
                                                 const float* __restrict__ W_in,
                                                 const float* __restrict__ b_in,
                                                 unsigned short* __restrict__ h0,
                                                 const float* __restrict__ Wsrc,
                                                 const float* __restrict__ Wdst,
                                                 unsigned short* __restrict__ Wpack) {
    int bid = blockIdx.x;
    if (bid < 12500) {
        int idx = bid * 256 + threadIdx.x;
        int node = idx >> 6, d = idx & 63;
        float acc = b_in[d];
        #pragma unroll
        for (int k = 0; k < 16; k++) acc += feat[node * 16 + k] * W_in[k * 64 + d];
        h0[idx] = f2bf(acc);
    } else {
        int pb = bid - 12500;                       // 0..255
        int mat = pb >> 7;                          // 0/1
        int idx = (pb & 127) * 256 + threadIdx.x;   // 0..32767
        const float* W = mat ? Wdst : Wsrc;
        int j = idx & 7;
        int lane = (idx >> 3) & 63;
        int q = (idx >> 9) & 3;
        int t = (idx >> 11) & 15;
        int col = t * 16 + (lane & 15);
        int k = q * 32 + (lane >> 4) * 8 + j;
        Wpack[mat * 32768 + idx] = f2bf(W[k * 256 + col]);
    }
}

// ---------------- CSR build ----------------
__global__ __launch_bounds__(256) void k_hist(const int* __restrict__ dst, int* __restrict__ indeg, int e) {
    int i = blockIdx.x * 256 + threadIdx.x;
    if (i < e) atomicAdd(&indeg[dst[i]], 1);
}

// per-512-chunk exclusive scan; write block sum; zero indeg (=cursor) in-place
__global__ __launch_bounds__(512) void k_scan_local(int* __restrict__ indeg,
                                                    int* __restrict__ offsets,
                                                    int* __restrict__ bsums, int n) {
    __shared__ int tmp[512];
    int t = threadIdx.x;
    int idx = blockIdx.x * 512 + t;
    int v = (idx < n) ? indeg[idx] : 0;
    tmp[t] = v;
    __syncthreads();
    #pragma unroll
    for (int off = 1; off < 512; off <<= 1) {
        int add = (t >= off) ? tmp[t - off] : 0;
        __syncthreads();
        tmp[t] += add;
        __syncthreads();
    }
    if (idx < n) { offsets[idx] = tmp[t] - v; indeg[idx] = 0; }
    if (t == 511) bsums[blockIdx.x] = tmp[511];
}

// single block: exclusive scan of <=128 block sums
__global__ __launch_bounds__(128) void k_scan_sums(int* __restrict__ bsums, int nb) {
    __shared__ int tmp[128];
    int t = threadIdx.x;
    int v = (t < nb) ? bsums[t] : 0;
    tmp[t] = v;
    __syncthreads();
    #pragma unroll
    for (int off = 1; off < 128; off <<= 1) {
        int add = (t >= off) ? tmp[t - off] : 0;
        __syncthreads();
        tmp[t] += add;
        __syncthreads();
    }
    if (t < nb) bsums[t] = tmp[t] - v;
}

__global__ __launch_bounds__(512) void k_scan_add(int* __restrict__ offsets,
                                                  const int* __restrict__ bsums, int n) {
    int idx = blockIdx.x * 512 + threadIdx.x;
    if (idx < n) offsets[idx] += bsums[blockIdx.x];
    if (idx == 0) offsets[n] = N_EDGES;
}

__global__ __launch_bounds__(256) void k_fill(const int* __restrict__ src, const int* __restrict__ dst,
                                              const int* __restrict__ offsets, int* __restrict__ cursor,
                                              int* __restrict__ csr_src, int e) {
    int i = blockIdx.x * 256 + threadIdx.x;
    if (i >= e) return;
    int d = dst[i];
    int slot = offsets[d] + atomicAdd(&cursor[d], 1);
    csr_src[slot] = src[i];
}

// ---------------- fs/fd = [h|h0] @ W + b  via MFMA, bf16 out [N,256] ----------------
__global__ __launch_bounds__(256) void k_gemm(const unsigned short* __restrict__ h,
                                              const unsigned short* __restrict__ h0,
                                              const unsigned short* __restrict__ Wpack,
                                              const float* __restrict__ bsrc,
                                              const float* __restrict__ bdst,
                                              unsigned short* __restrict__ fs,
                                              unsigned short* __restrict__ fd, int n) {
    int mat = blockIdx.y;
    const unsigned short* Wp = Wpack + mat * 32768;
    const float* bias = mat ? bdst : bsrc;
    unsigned short* out = mat ? fd : fs;
    int wave = threadIdx.x >> 6, lane = threadIdx.x & 63;
    int quad = lane >> 4, m16 = lane & 15;
    int row0 = blockIdx.x * 128 + wave * 32;

    floatx4 acc[2][16];
    #pragma unroll
    for (int f = 0; f < 2; f++)
        #pragma unroll
        for (int t = 0; t < 16; t++) acc[f][t] = (floatx4){0.f, 0.f, 0.f, 0.f};

    #pragma unroll
    for (int q = 0; q < 4; q++) {
        int kk = q * 32 + quad * 8;
        short8 a[2];
        #pragma unroll
        for (int f = 0; f < 2; f++) {
            int r = row0 + f * 16 + m16;
            if (r > n - 1) r = n - 1;
            const unsigned short* base = (kk < 64) ? (h + (size_t)r * 64 + kk)
                                                   : (h0 + (size_t)r * 64 + (kk - 64));
            a[f] = *(const short8*)base;
        }
        #pragma unroll
        for (int t = 0; t < 16; t++) {
            short8 b = *(const short8*)(Wp + ((size_t)(t * 4 + q) * 64 + lane) * 8);
            acc[0][t] = __builtin_amdgcn_mfma_f32_16x16x32_bf16(a[0], b, acc[0][t], 0, 0, 0);
            acc[1][t] = __builtin_amdgcn_mfma_f32_16x16x32_bf16(a[1], b, acc[1][t], 0, 0, 0);
        }
    }
    #pragma unroll
    for (int f = 0; f < 2; f++) {
        #pragma unroll
        for (int t = 0; t < 16; t++) {
            int col = t * 16 + m16;
            float bb = bias[col];
            #pragma unroll
            for (int r = 0; r < 4; r++) {
                int row = row0 + f * 16 + quad * 4 + r;
                if (row < n) out[(size_t)row * 256 + col] = f2bf(acc[f][t][r] + bb);
            }
        }
    }
}

// ---------------- per-node online-softmax aggregation (bf16 fs/fd) ----------------
// one wave per node; lane = (head = lane>>4, dims (lane&15)*4..+3); 2-edge unroll
__global__ __launch_bounds__(256) void k_agg(const unsigned short* __restrict__ fs,
                                             const unsigned short* __restrict__ fd,
                                             const int* __restrict__ offsets,
                                             const int* __restrict__ csr_src,
                                             const float* __restrict__ attn,
                                             unsigned short* __restrict__ hout, int n) {
    int wave = threadIdx.x >> 6;
    int lane = threadIdx.x & 63;
    int node = blockIdx.x * 4 + wave;
    if (node >= n) return;
    int dg = lane & 15;

    float4 at = *(const float4*)(attn + lane * 4);
    ushort4 fdb = *(const ushort4*)(fd + (size_t)node * 256 + lane * 4);
    float fdv[4] = {bf2f(fdb.x), bf2f(fdb.y), bf2f(fdb.z), bf2f(fdb.w)};
    float atv[4] = {at.x, at.y, at.z, at.w};

    float m = -INFINITY, l = 0.f;
    float acc[4] = {0.f, 0.f, 0.f, 0.f};

    int beg = offsets[node], end = offsets[node + 1];
    int j = beg;
    for (; j + 2 <= end; j += 2) {
        int s0 = csr_src[j];
        int s1 = csr_src[j + 1];
        ushort4 fb0 = *(const ushort4*)(fs + (size_t)s0 * 256 + lane * 4);
        ushort4 fb1 = *(const ushort4*)(fs + (size_t)s1 * 256 + lane * 4);
        float f0[4] = {bf2f(fb0.x), bf2f(fb0.y), bf2f(fb0.z), bf2f(fb0.w)};
        float f1[4] = {bf2f(fb1.x), bf2f(fb1.y), bf2f(fb1.z), bf2f(fb1.w)};
        float p0 = 0.f, p1 = 0.f;
        #pragma unroll
        for (int k = 0; k < 4; k++) {
            float e0 = f0[k] + fdv[k];
            float e1 = f1[k] + fdv[k];
            e0 = (e0 > 0.f) ? e0 : NEG_SLOPE * e0;
            e1 = (e1 > 0.f) ? e1 : NEG_SLOPE * e1;
            p0 += atv[k] * e0;
            p1 += atv[k] * e1;
        }
        p0 += __shfl_xor(p0, 1, 64); p1 += __shfl_xor(p1, 1, 64);
        p0 += __shfl_xor(p0, 2, 64); p1 += __shfl_xor(p1, 2, 64);
        p0 += __shfl_xor(p0, 4, 64); p1 += __shfl_xor(p1, 4, 64);
        p0 += __shfl_xor(p0, 8, 64); p1 += __shfl_xor(p1, 8, 64);
        float nm = fmaxf(m, fmaxf(p0, p1));
        float sc = __expf(m - nm);
        float w0 = __expf(p0 - nm);
        float w1 = __expf(p1 - nm);
        l = l * sc + w0 + w1;
        m = nm;
        #pragma unroll
        for (int k = 0; k < 4; k++) acc[k] = acc[k] * sc + w0 * f0[k] + w1 * f1[k];
    }
    if (j < end) {
        int s = csr_src[j];
        ushort4 fsb = *(const ushort4*)(fs + (size_t)s * 256 + lane * 4);
        float fv[4] = {bf2f(fsb.x), bf2f(fsb.y), bf2f(fsb.z), bf2f(fsb.w)};
        float p = 0.f;
        #pragma unroll
        for (int k = 0; k < 4; k++) {
            float e = fv[k] + fdv[k];
            e = (e > 0.f) ? e : NEG_SLOPE * e;
            p += atv[k] * e;
        }
        p += __shfl_xor(p, 1, 64);
        p += __shfl_xor(p, 2, 64);
        p += __shfl_xor(p, 4, 64);
        p += __shfl_xor(p, 8, 64);
        float nm = fmaxf(m, p);
        float sc = __expf(m - nm);
        float w = __expf(p - nm);
        l = l * sc + w;
        m = nm;
        #pragma unroll
        for (int k = 0; k < 4; k++) acc[k] = acc[k] * sc + w * fv[k];
    }
    float o[4];
    float inv = (l > 0.f) ? 1.f / l : 0.f;
    #pragma unroll
    for (int k = 0; k < 4; k++) o[k] = tanhf(acc[k] * inv);
    #pragma unroll
    for (int k = 0; k < 4; k++) {
        o[k] += __shfl_xor(o[k], 16, 64);
        o[k] += __shfl_xor(o[k], 32, 64);
    }
    if (lane < 16) {
        ushort4 ov = {f2bf(o[0]), f2bf(o[1]), f2bf(o[2]), f2bf(o[3])};
        *(ushort4*)(hout + (size_t)node * 64 + dg * 4) = ov;
    }
}

// ---------------- graph readout ----------------
__global__ __launch_bounds__(256) void k_readout(const unsigned short* __restrict__ h,
                                                 const float* __restrict__ is_root,
                                                 const int* __restrict__ gid, float* __restrict__ hg, int n) {
    __shared__ float s_hg[N_GRAPHS * 64];
    int t = threadIdx.x;
    for (int i = t; i < N_GRAPHS * 64; i += 256) s_hg[i] = 0.f;
    __syncthreads();
    int d = t & 63;
    int local = t >> 6;
    int start = blockIdx.x * 1024;
    int stop = min(start + 1024, n);
    for (int i = start + local; i < stop; i += 4) {
        float v = bf2f(h[(size_t)i * 64 + d]) * is_root[i];
        atomicAdd(&s_hg[gid[i] * 64 + d], v);
    }
    __syncthreads();
    for (int i = t; i < N_GRAPHS * 64; i += 256) atomicAdd(&hg[i], s_hg[i]);
}

__global__ __launch_bounds__(512) void k_out(const float* __restrict__ hg, const float* __restrict__ W_out,
                                             const float* __restrict__ b_out, float* __restrict__ out) {
    int t = threadIdx.x;
    if (t >= N_GRAPHS * 32) return;
    int b = t >> 5, c = t & 31;
    float a = b_out[c];
    #pragma unroll
    for (int d = 0; d < 64; d++) a += hg[b * 64 + d] * W_out[d * 32 + c];
    out[t] = a;
}

extern "C" void kernel_launch(void* const* d_in, const int* in_sizes, int n_in,
                              void* d_out, int out_size, void* d_ws, size_t ws_size,
                              hipStream_t stream) {
    const float* feat    = (const float*)d_in[0];
    const float* is_root = (const float*)d_in[1];
    const int*   src     = (const int*)d_in[2];
    const int*   dst     = (const int*)d_in[3];
    const int*   gid     = (const int*)d_in[4];
    const float* W_in    = (const float*)d_in[5];
    const float* b_in    = (const float*)d_in[6];
    const float* W_src   = (const float*)d_in[7];
    const float* b_src   = (const float*)d_in[8];
    const float* W_dst   = (const float*)d_in[9];
    const float* b_dst   = (const float*)d_in[10];
    const float* attn    = (const float*)d_in[11];
    const float* W_out   = (const float*)d_in[12];
    const float* b_out   = (const float*)d_in[13];
    float* out = (float*)d_out;

    char* ws = (char*)d_ws;
    size_t off = 0;
    auto take = [&](size_t bytes) -> char* {
        char* p = ws + off;
        off = (off + bytes + 255) & ~(size_t)255;
        return p;
    };
    unsigned short* fs    = (unsigned short*)take((size_t)N_NODES * 256 * 2);
    unsigned short* fd    = (unsigned short*)take((size_t)N_NODES * 256 * 2);
    unsigned short* h0    = (unsigned short*)take((size_t)N_NODES * 64 * 2);
    unsigned short* hA    = (unsigned short*)take((size_t)N_NODES * 64 * 2);
    unsigned short* hB    = (unsigned short*)take((size_t)N_NODES * 64 * 2);
    unsigned short* Wpack = (unsigned short*)take((size_t)2 * 32768 * 2);
    float* hg             = (float*)take((size_t)N_GRAPHS * 64 * 4);
    int*   offsets        = (int*)take((size_t)(N_NODES + 1) * 4);
    int*   cursor         = (int*)take((size_t)N_NODES * 4);
    int*   csr_src        = (int*)take((size_t)N_EDGES * 4);
    int*   bsums          = (int*)take((size_t)128 * 4);

    const int n = N_NODES, e = N_EDGES;
    const int nb = (n + 511) / 512;  // 98
    dim3 b256(256);

    k_init<<<dim3((n + 255) / 256), b256, 0, stream>>>(cursor, hg);
    k_h0_pack<<<dim3(12756), b256, 0, stream>>>(feat, W_in, b_in, h0, W_src, W_dst, Wpack);

    // CSR build
    k_hist<<<dim3((e + 255) / 256), b256, 0, stream>>>(dst, cursor, e);
    k_scan_local<<<dim3(nb), dim3(512), 0, stream>>>(cursor, offsets, bsums, n);
    k_scan_sums<<<dim3(1), dim3(128), 0, stream>>>(bsums, nb);
    k_scan_add<<<dim3(nb), dim3(512), 0, stream>>>(offsets, bsums, n);
    k_fill<<<dim3((e + 255) / 256), b256, 0, stream>>>(src, dst, offsets, cursor, csr_src, e);

    // 4 GATv2 layers
    const unsigned short* hin = h0;
    unsigned short* houts[4] = { hA, hB, hA, hB };
    for (int layer = 0; layer < 4; layer++) {
        k_gemm<<<dim3((n + 127) / 128, 2), b256, 0, stream>>>(hin, h0, Wpack, b_src, b_dst, fs, fd, n);
        k_agg<<<dim3((n + 3) / 4), b256, 0, stream>>>(fs, fd, offsets, csr_src, attn, houts[layer], n);
        hin = houts[layer];
    }

    // readout
    k_readout<<<dim3((n + 1023) / 1024), b256, 0, stream>>>(hB, is_root, gid, hg, n);
    k_out<<<dim3(1), dim3(512), 0, stream>>>(hg, W_out, b_out, out);
}

// Round 4
// 552.997 us; speedup vs baseline: 2.4100x; 1.3057x over previous
//
#include <hip/hip_runtime.h>
#include <math.h>

#define N_NODES 50000
#define N_EDGES 400000
#define N_GRAPHS 16
#define HEADS 4
#define NEG_SLOPE 0.2f

typedef __attribute__((ext_vector_type(8))) short short8;
typedef __attribute__((ext_vector_type(4))) float floatx4;

__device__ __forceinline__ unsigned short f2bf(float x) {
    union { float f; unsigned int u; } v; v.f = x;
    unsigned int r = v.u + 0x7fffu + ((v.u >> 16) & 1u);
    return (unsigned short)(r >> 16);
}
__device__ __forceinline__ float bf2f(unsigned short b) {
    union { unsigned int u; float f; } v; v.u = ((unsigned int)b) << 16;
    return v.f;
}

// ---------------- init: zero cursor + hg ----------------
__global__ __launch_bounds__(256) void k_init(int* __restrict__ cursor, float* __restrict__ hg) {
    int i = blockIdx.x * 256 + threadIdx.x;
    if (i < N_NODES) cursor[i] = 0;
    if (i < N_GRAPHS * 64) hg[i] = 0.f;
}

// ---------------- fused h0 + weight pack ----------------
// Wpack layout (A-frag, 16x16x32): Wpack[mat][(t*4+q)*64+lane][j] = W[q*32+(lane>>4)*8+j][t*16+(lane&15)]
__global__ __launch_bounds__(256) void k_h0_pack(const float* __restrict__ feat,
                                                 const float* __restrict__ W_in,
                                                 const float* __restrict__ b_in,
                                                 unsigned short* __restrict__ h0,
                                                 const float* __restrict__ Wsrc,
                                                 const float* __restrict__ Wdst,
                                                 unsigned short* __restrict__ Wpack) {
    int bid = blockIdx.x;
    if (bid < 12500) {
        int idx = bid * 256 + threadIdx.x;
        int node = idx >> 6, d = idx & 63;
        float acc = b_in[d];
        #pragma unroll
        for (int k = 0; k < 16; k++) acc += feat[node * 16 + k] * W_in[k * 64 + d];
        h0[idx] = f2bf(acc);
    } else {
        int pb = bid - 12500;                       // 0..255
        int mat = pb >> 7;                          // 0/1
        int idx = (pb & 127) * 256 + threadIdx.x;   // 0..32767
        const float* W = mat ? Wdst : Wsrc;
        int j = idx & 7;
        int lane = (idx >> 3) & 63;
        int q = (idx >> 9) & 3;
        int t = (idx >> 11) & 15;
        int col = t * 16 + (lane & 15);
        int k = q * 32 + (lane >> 4) * 8 + j;
        Wpack[mat * 32768 + idx] = f2bf(W[k * 256 + col]);
    }
}

// ---------------- CSR build ----------------
__global__ __launch_bounds__(256) void k_hist(const int* __restrict__ dst, int* __restrict__ indeg, int e) {
    int i = blockIdx.x * 256 + threadIdx.x;
    if (i < e) atomicAdd(&indeg[dst[i]], 1);
}

__global__ __launch_bounds__(512) void k_scan_local(int* __restrict__ indeg,
                                                    int* __restrict__ offsets,
                                                    int* __restrict__ bsums, int n) {
    __shared__ int tmp[512];
    int t = threadIdx.x;
    int idx = blockIdx.x * 512 + t;
    int v = (idx < n) ? indeg[idx] : 0;
    tmp[t] = v;
    __syncthreads();
    #pragma unroll
    for (int off = 1; off < 512; off <<= 1) {
        int add = (t >= off) ? tmp[t - off] : 0;
        __syncthreads();
        tmp[t] += add;
        __syncthreads();
    }
    if (idx < n) { offsets[idx] = tmp[t] - v; indeg[idx] = 0; }
    if (t == 511) bsums[blockIdx.x] = tmp[511];
}

__global__ __launch_bounds__(128) void k_scan_sums(int* __restrict__ bsums, int nb) {
    __shared__ int tmp[128];
    int t = threadIdx.x;
    int v = (t < nb) ? bsums[t] : 0;
    tmp[t] = v;
    __syncthreads();
    #pragma unroll
    for (int off = 1; off < 128; off <<= 1) {
        int add = (t >= off) ? tmp[t - off] : 0;
        __syncthreads();
        tmp[t] += add;
        __syncthreads();
    }
    if (t < nb) bsums[t] = tmp[t] - v;
}

__global__ __launch_bounds__(512) void k_scan_add(int* __restrict__ offsets,
                                                  const int* __restrict__ bsums, int n) {
    int idx = blockIdx.x * 512 + threadIdx.x;
    if (idx < n) offsets[idx] += bsums[blockIdx.x];
    if (idx == 0) offsets[n] = N_EDGES;
}

__global__ __launch_bounds__(256) void k_fill(const int* __restrict__ src, const int* __restrict__ dst,
                                              const int* __restrict__ offsets, int* __restrict__ cursor,
                                              int* __restrict__ csr_src, int e) {
    int i = blockIdx.x * 256 + threadIdx.x;
    if (i >= e) return;
    int d = dst[i];
    int slot = offsets[d] + atomicAdd(&cursor[d], 1);
    csr_src[slot] = src[i];
}

// ---------------- fs/fd = [h|h0] @ W + b  via MFMA (A=W, B=X^T) ----------------
// D row = out-feature, col = node -> lane packs ushort4 of 4 consecutive features.
// block 256 = 4 waves; wave: 32 nodes x 256 feats; grid.x = ceil(n/128), grid.y = 2
__global__ __launch_bounds__(256) void k_gemm(const unsigned short* __restrict__ h,
                                              const unsigned short* __restrict__ h0,
                                              const unsigned short* __restrict__ Wpack,
                                              const float* __restrict__ bsrc,
                                              const float* __restrict__ bdst,
                                              unsigned short* __restrict__ fs,
                                              unsigned short* __restrict__ fd, int n) {
    int mat = blockIdx.y;
    const unsigned short* Wp = Wpack + mat * 32768;
    const float* bias = mat ? bdst : bsrc;
    unsigned short* out = mat ? fd : fs;
    int wave = threadIdx.x >> 6, lane = threadIdx.x & 63;
    int quad = lane >> 4, m16 = lane & 15;
    int node0 = blockIdx.x * 128 + wave * 32;

    floatx4 acc[2][16];
    #pragma unroll
    for (int f = 0; f < 2; f++)
        #pragma unroll
        for (int t = 0; t < 16; t++) acc[f][t] = (floatx4){0.f, 0.f, 0.f, 0.f};

    #pragma unroll
    for (int q = 0; q < 4; q++) {
        int kk = q * 32 + quad * 8;
        short8 x[2];
        #pragma unroll
        for (int f = 0; f < 2; f++) {
            int r = node0 + f * 16 + m16;
            if (r > n - 1) r = n - 1;
            const unsigned short* base = (kk < 64) ? (h + (size_t)r * 64 + kk)
                                                   : (h0 + (size_t)r * 64 + (kk - 64));
            x[f] = *(const short8*)base;
        }
        #pragma unroll
        for (int t = 0; t < 16; t++) {
            short8 w = *(const short8*)(Wp + ((size_t)(t * 4 + q) * 64 + lane) * 8);
            acc[0][t] = __builtin_amdgcn_mfma_f32_16x16x32_bf16(w, x[0], acc[0][t], 0, 0, 0);
            acc[1][t] = __builtin_amdgcn_mfma_f32_16x16x32_bf16(w, x[1], acc[1][t], 0, 0, 0);
        }
    }
    // epilogue: feature = t*16 + quad*4 + r, node = node0 + f*16 + m16
    #pragma unroll
    for (int f = 0; f < 2; f++) {
        int node = node0 + f * 16 + m16;
        if (node >= n) continue;
        #pragma unroll
        for (int t = 0; t < 16; t++) {
            int fbase = t * 16 + quad * 4;
            float4 bb = *(const float4*)(bias + fbase);
            ushort4 ov = { f2bf(acc[f][t][0] + bb.x), f2bf(acc[f][t][1] + bb.y),
                           f2bf(acc[f][t][2] + bb.z), f2bf(acc[f][t][3] + bb.w) };
            *(ushort4*)(out + (size_t)node * 256 + fbase) = ov;
        }
    }
}

// ---------------- per-node online-softmax aggregation (bf16 fs/fd) ----------------
// one wave per node; lane = (head = lane>>4, dims (lane&15)*4..+3); 4-edge unroll
__global__ __launch_bounds__(256) void k_agg(const unsigned short* __restrict__ fs,
                                             const unsigned short* __restrict__ fd,
                                             const int* __restrict__ offsets,
                                             const int* __restrict__ csr_src,
                                             const float* __restrict__ attn,
                                             unsigned short* __restrict__ hout, int n) {
    int wave = threadIdx.x >> 6;
    int lane = threadIdx.x & 63;
    int node = blockIdx.x * 4 + wave;
    if (node >= n) return;

    float4 at = *(const float4*)(attn + lane * 4);
    ushort4 fdb = *(const ushort4*)(fd + (size_t)node * 256 + lane * 4);
    float fdv[4] = {bf2f(fdb.x), bf2f(fdb.y), bf2f(fdb.z), bf2f(fdb.w)};
    float atv[4] = {at.x, at.y, at.z, at.w};

    float m = -INFINITY, l = 0.f;
    float acc[4] = {0.f, 0.f, 0.f, 0.f};

    int beg = offsets[node], end = offsets[node + 1];
    int j = beg;
    for (; j + 4 <= end; j += 4) {
        int s0 = csr_src[j], s1 = csr_src[j + 1], s2 = csr_src[j + 2], s3 = csr_src[j + 3];
        ushort4 b0 = *(const ushort4*)(fs + (size_t)s0 * 256 + lane * 4);
        ushort4 b1 = *(const ushort4*)(fs + (size_t)s1 * 256 + lane * 4);
        ushort4 b2 = *(const ushort4*)(fs + (size_t)s2 * 256 + lane * 4);
        ushort4 b3 = *(const ushort4*)(fs + (size_t)s3 * 256 + lane * 4);
        float f0[4] = {bf2f(b0.x), bf2f(b0.y), bf2f(b0.z), bf2f(b0.w)};
        float f1[4] = {bf2f(b1.x), bf2f(b1.y), bf2f(b1.z), bf2f(b1.w)};
        float f2[4] = {bf2f(b2.x), bf2f(b2.y), bf2f(b2.z), bf2f(b2.w)};
        float f3[4] = {bf2f(b3.x), bf2f(b3.y), bf2f(b3.z), bf2f(b3.w)};
        float p0 = 0.f, p1 = 0.f, p2 = 0.f, p3 = 0.f;
        #pragma unroll
        for (int k = 0; k < 4; k++) {
            float e0 = f0[k] + fdv[k], e1 = f1[k] + fdv[k];
            float e2 = f2[k] + fdv[k], e3 = f3[k] + fdv[k];
            e0 = (e0 > 0.f) ? e0 : NEG_SLOPE * e0;
            e1 = (e1 > 0.f) ? e1 : NEG_SLOPE * e1;
            e2 = (e2 > 0.f) ? e2 : NEG_SLOPE * e2;
            e3 = (e3 > 0.f) ? e3 : NEG_SLOPE * e3;
            p0 += atv[k] * e0; p1 += atv[k] * e1;
            p2 += atv[k] * e2; p3 += atv[k] * e3;
        }
        #pragma unroll
        for (int off = 1; off <= 8; off <<= 1) {
            p0 += __shfl_xor(p0, off, 64);
            p1 += __shfl_xor(p1, off, 64);
            p2 += __shfl_xor(p2, off, 64);
            p3 += __shfl_xor(p3, off, 64);
        }
        float nm = fmaxf(fmaxf(m, fmaxf(p0, p1)), fmaxf(p2, p3));
        float sc = __expf(m - nm);
        float w0 = __expf(p0 - nm), w1 = __expf(p1 - nm);
        float w2 = __expf(p2 - nm), w3 = __expf(p3 - nm);
        l = l * sc + w0 + w1 + w2 + w3;
        m = nm;
        #pragma unroll
        for (int k = 0; k < 4; k++)
            acc[k] = acc[k] * sc + w0 * f0[k] + w1 * f1[k] + w2 * f2[k] + w3 * f3[k];
    }
    for (; j < end; j++) {
        int s = csr_src[j];
        ushort4 fsb = *(const ushort4*)(fs + (size_t)s * 256 + lane * 4);
        float fv[4] = {bf2f(fsb.x), bf2f(fsb.y), bf2f(fsb.z), bf2f(fsb.w)};
        float p = 0.f;
        #pragma unroll
        for (int k = 0; k < 4; k++) {
            float e = fv[k] + fdv[k];
            e = (e > 0.f) ? e : NEG_SLOPE * e;
            p += atv[k] * e;
        }
        p += __shfl_xor(p, 1, 64);
        p += __shfl_xor(p, 2, 64);
        p += __shfl_xor(p, 4, 64);
        p += __shfl_xor(p, 8, 64);
        float nm = fmaxf(m, p);
        float sc = __expf(m - nm);
        float w = __expf(p - nm);
        l = l * sc + w;
        m = nm;
        #pragma unroll
        for (int k = 0; k < 4; k++) acc[k] = acc[k] * sc + w * fv[k];
    }
    float o[4];
    float inv = (l > 0.f) ? 1.f / l : 0.f;
    #pragma unroll
    for (int k = 0; k < 4; k++) o[k] = tanhf(acc[k] * inv);
    #pragma unroll
    for (int k = 0; k < 4; k++) {
        o[k] += __shfl_xor(o[k], 16, 64);
        o[k] += __shfl_xor(o[k], 32, 64);
    }
    if (lane < 16) {
        ushort4 ov = {f2bf(o[0]), f2bf(o[1]), f2bf(o[2]), f2bf(o[3])};
        *(ushort4*)(hout + (size_t)node * 64 + (lane & 15) * 4) = ov;
    }
}

// ---------------- graph readout: wave per 32 nodes, register accumulate ----------------
__global__ __launch_bounds__(256) void k_readout(const unsigned short* __restrict__ h,
                                                 const float* __restrict__ is_root,
                                                 const int* __restrict__ gid, float* __restrict__ hg, int n) {
    int wave = threadIdx.x >> 6, lane = threadIdx.x & 63;
    int start = blockIdx.x * 128 + wave * 32;
    if (start >= n) return;
    int stop = min(start + 32, n);
    float acc = 0.f;
    int cur = gid[start];
    for (int i = start; i < stop; i++) {
        int g = gid[i];
        if (g != cur) {                     // wave-uniform branch (sorted gid)
            atomicAdd(&hg[cur * 64 + lane], acc);
            acc = 0.f;
            cur = g;
        }
        acc += bf2f(h[(size_t)i * 64 + lane]) * is_root[i];
    }
    atomicAdd(&hg[cur * 64 + lane], acc);
}

__global__ __launch_bounds__(512) void k_out(const float* __restrict__ hg, const float* __restrict__ W_out,
                                             const float* __restrict__ b_out, float* __restrict__ out) {
    int t = threadIdx.x;
    if (t >= N_GRAPHS * 32) return;
    int b = t >> 5, c = t & 31;
    float a = b_out[c];
    #pragma unroll
    for (int d = 0; d < 64; d++) a += hg[b * 64 + d] * W_out[d * 32 + c];
    out[t] = a;
}

extern "C" void kernel_launch(void* const* d_in, const int* in_sizes, int n_in,
                              void* d_out, int out_size, void* d_ws, size_t ws_size,
                              hipStream_t stream) {
    const float* feat    = (const float*)d_in[0];
    const float* is_root = (const float*)d_in[1];
    const int*   src     = (const int*)d_in[2];
    const int*   dst     = (const int*)d_in[3];
    const int*   gid     = (const int*)d_in[4];
    const float* W_in    = (const float*)d_in[5];
    const float* b_in    = (const float*)d_in[6];
    const float* W_src   = (const float*)d_in[7];
    const float* b_src   = (const float*)d_in[8];
    const float* W_dst   = (const float*)d_in[9];
    const float* b_dst   = (const float*)d_in[10];
    const float* attn    = (const float*)d_in[11];
    const float* W_out   = (const float*)d_in[12];
    const float* b_out   = (const float*)d_in[13];
    float* out = (float*)d_out;

    char* ws = (char*)d_ws;
    size_t off = 0;
    auto take = [&](size_t bytes) -> char* {
        char* p = ws + off;
        off = (off + bytes + 255) & ~(size_t)255;
        return p;
    };
    unsigned short* fs    = (unsigned short*)take((size_t)N_NODES * 256 * 2);
    unsigned short* fd    = (unsigned short*)take((size_t)N_NODES * 256 * 2);
    unsigned short* h0    = (unsigned short*)take((size_t)N_NODES * 64 * 2);
    unsigned short* hA    = (unsigned short*)take((size_t)N_NODES * 64 * 2);
    unsigned short* hB    = (unsigned short*)take((size_t)N_NODES * 64 * 2);
    unsigned short* Wpack = (unsigned short*)take((size_t)2 * 32768 * 2);
    float* hg             = (float*)take((size_t)N_GRAPHS * 64 * 4);
    int*   offsets        = (int*)take((size_t)(N_NODES + 1) * 4);
    int*   cursor         = (int*)take((size_t)N_NODES * 4);
    int*   csr_src        = (int*)take((size_t)N_EDGES * 4);
    int*   bsums          = (int*)take((size_t)128 * 4);

    const int n = N_NODES, e = N_EDGES;
    const int nb = (n + 511) / 512;  // 98
    dim3 b256(256);

    k_init<<<dim3((n + 255) / 256), b256, 0, stream>>>(cursor, hg);
    k_h0_pack<<<dim3(12756), b256, 0, stream>>>(feat, W_in, b_in, h0, W_src, W_dst, Wpack);

    // CSR build
    k_hist<<<dim3((e + 255) / 256), b256, 0, stream>>>(dst, cursor, e);
    k_scan_local<<<dim3(nb), dim3(512), 0, stream>>>(cursor, offsets, bsums, n);
    k_scan_sums<<<dim3(1), dim3(128), 0, stream>>>(bsums, nb);
    k_scan_add<<<dim3(nb), dim3(512), 0, stream>>>(offsets, bsums, n);
    k_fill<<<dim3((e + 255) / 256), b256, 0, stream>>>(src, dst, offsets, cursor, csr_src, e);

    // 4 GATv2 layers
    const unsigned short* hin = h0;
    unsigned short* houts[4] = { hA, hB, hA, hB };
    for (int layer = 0; layer < 4; layer++) {
        k_gemm<<<dim3((n + 127) / 128, 2), b256, 0, stream>>>(hin, h0, Wpack, b_src, b_dst, fs, fd, n);
        k_agg<<<dim3((n + 3) / 4), b256, 0, stream>>>(fs, fd, offsets, csr_src, attn, houts[layer], n);
        hin = houts[layer];
    }

    // readout
    k_readout<<<dim3((n + 127) / 128), b256, 0, stream>>>(hB, is_root, gid, hg, n);
    k_out<<<dim3(1), dim3(512), 0, stream>>>(hg, W_out, b_out, out);
}

// Round 5
// 524.629 us; speedup vs baseline: 2.5404x; 1.0541x over previous
//
#include <hip/hip_runtime.h>
#include <math.h>

#define N_NODES 50000
#define N_EDGES 400000
#define N_GRAPHS 16
#define HEADS 4
#define NEG_SLOPE 0.2f

typedef __attribute__((ext_vector_type(8))) short short8;
typedef __attribute__((ext_vector_type(4))) float floatx4;

__device__ __forceinline__ unsigned short f2bf(float x) {
    union { float f; unsigned int u; } v; v.f = x;
    unsigned int r = v.u + 0x7fffu + ((v.u >> 16) & 1u);
    return (unsigned short)(r >> 16);
}
__device__ __forceinline__ float bf2f(unsigned short b) {
    union { unsigned int u; float f; } v; v.u = ((unsigned int)b) << 16;
    return v.f;
}
// two packed bf16 -> two f32 in 2 VALU ops
__device__ __forceinline__ void bf2f2(unsigned int u, float& lo, float& hi) {
    union { unsigned int i; float f; } a, b;
    a.i = u << 16; b.i = u & 0xffff0000u;
    lo = a.f; hi = b.f;
}
__device__ __forceinline__ float fast_tanh(float x) {
    float e = __expf(2.f * x);
    return 1.f - 2.f / (e + 1.f);
}
__device__ __forceinline__ float lrelu(float e) {
    return fmaxf(e, NEG_SLOPE * e);
}

// ---------------- init: zero cursor + hg ----------------
__global__ __launch_bounds__(256) void k_init(int* __restrict__ cursor, float* __restrict__ hg) {
    int i = blockIdx.x * 256 + threadIdx.x;
    if (i < N_NODES) cursor[i] = 0;
    if (i < N_GRAPHS * 64) hg[i] = 0.f;
}

// ---------------- fused h0 + weight pack ----------------
__global__ __launch_bounds__(256) void k_h0_pack(const float* __restrict__ feat,
                                                 const float* __restrict__ W_in,
                                                 const float* __restrict__ b_in,
                                                 unsigned short* __restrict__ h0,
                                                 const float* __restrict__ Wsrc,
                                                 const float* __restrict__ Wdst,
                                                 unsigned short* __restrict__ Wpack) {
    int bid = blockIdx.x;
    if (bid < 12500) {
        int idx = bid * 256 + threadIdx.x;
        int node = idx >> 6, d = idx & 63;
        float acc = b_in[d];
        #pragma unroll
        for (int k = 0; k < 16; k++) acc += feat[node * 16 + k] * W_in[k * 64 + d];
        h0[idx] = f2bf(acc);
    } else {
        int pb = bid - 12500;                       // 0..255
        int mat = pb >> 7;                          // 0/1
        int idx = (pb & 127) * 256 + threadIdx.x;   // 0..32767
        const float* W = mat ? Wdst : Wsrc;
        int j = idx & 7;
        int lane = (idx >> 3) & 63;
        int q = (idx >> 9) & 3;
        int t = (idx >> 11) & 15;
        int col = t * 16 + (lane & 15);
        int k = q * 32 + (lane >> 4) * 8 + j;
        Wpack[mat * 32768 + idx] = f2bf(W[k * 256 + col]);
    }
}

// ---------------- CSR build ----------------
__global__ __launch_bounds__(256) void k_hist(const int* __restrict__ dst, int* __restrict__ indeg, int e) {
    int i = blockIdx.x * 256 + threadIdx.x;
    if (i < e) atomicAdd(&indeg[dst[i]], 1);
}

__global__ __launch_bounds__(512) void k_scan_local(int* __restrict__ indeg,
                                                    int* __restrict__ offsets,
                                                    int* __restrict__ bsums, int n) {
    __shared__ int tmp[512];
    int t = threadIdx.x;
    int idx = blockIdx.x * 512 + t;
    int v = (idx < n) ? indeg[idx] : 0;
    tmp[t] = v;
    __syncthreads();
    #pragma unroll
    for (int off = 1; off < 512; off <<= 1) {
        int add = (t >= off) ? tmp[t - off] : 0;
        __syncthreads();
        tmp[t] += add;
        __syncthreads();
    }
    if (idx < n) { offsets[idx] = tmp[t] - v; indeg[idx] = 0; }
    if (t == 511) bsums[blockIdx.x] = tmp[511];
}

__global__ __launch_bounds__(128) void k_scan_sums(int* __restrict__ bsums, int nb) {
    __shared__ int tmp[128];
    int t = threadIdx.x;
    int v = (t < nb) ? bsums[t] : 0;
    tmp[t] = v;
    __syncthreads();
    #pragma unroll
    for (int off = 1; off < 128; off <<= 1) {
        int add = (t >= off) ? tmp[t - off] : 0;
        __syncthreads();
        tmp[t] += add;
        __syncthreads();
    }
    if (t < nb) bsums[t] = tmp[t] - v;
}

__global__ __launch_bounds__(512) void k_scan_add(int* __restrict__ offsets,
                                                  const int* __restrict__ bsums, int n) {
    int idx = blockIdx.x * 512 + threadIdx.x;
    if (idx < n) offsets[idx] += bsums[blockIdx.x];
    if (idx == 0) offsets[n] = N_EDGES;
}

__global__ __launch_bounds__(256) void k_fill(const int* __restrict__ src, const int* __restrict__ dst,
                                              const int* __restrict__ offsets, int* __restrict__ cursor,
                                              int* __restrict__ csr_src, int e) {
    int i = blockIdx.x * 256 + threadIdx.x;
    if (i >= e) return;
    int d = dst[i];
    int slot = offsets[d] + atomicAdd(&cursor[d], 1);
    csr_src[slot] = src[i];
}

// ---------------- fs/fd = [h|h0] @ W + b  via MFMA (A=W, B=X^T) ----------------
__global__ __launch_bounds__(256) void k_gemm(const unsigned short* __restrict__ h,
                                              const unsigned short* __restrict__ h0,
                                              const unsigned short* __restrict__ Wpack,
                                              const float* __restrict__ bsrc,
                                              const float* __restrict__ bdst,
                                              unsigned short* __restrict__ fs,
                                              unsigned short* __restrict__ fd, int n) {
    int mat = blockIdx.y;
    const unsigned short* Wp = Wpack + mat * 32768;
    const float* bias = mat ? bdst : bsrc;
    unsigned short* out = mat ? fd : fs;
    int wave = threadIdx.x >> 6, lane = threadIdx.x & 63;
    int quad = lane >> 4, m16 = lane & 15;
    int node0 = blockIdx.x * 128 + wave * 32;

    floatx4 acc[2][16];
    #pragma unroll
    for (int f = 0; f < 2; f++)
        #pragma unroll
        for (int t = 0; t < 16; t++) acc[f][t] = (floatx4){0.f, 0.f, 0.f, 0.f};

    #pragma unroll
    for (int q = 0; q < 4; q++) {
        int kk = q * 32 + quad * 8;
        short8 x[2];
        #pragma unroll
        for (int f = 0; f < 2; f++) {
            int r = node0 + f * 16 + m16;
            if (r > n - 1) r = n - 1;
            const unsigned short* base = (kk < 64) ? (h + (size_t)r * 64 + kk)
                                                   : (h0 + (size_t)r * 64 + (kk - 64));
            x[f] = *(const short8*)base;
        }
        #pragma unroll
        for (int t = 0; t < 16; t++) {
            short8 w = *(const short8*)(Wp + ((size_t)(t * 4 + q) * 64 + lane) * 8);
            acc[0][t] = __builtin_amdgcn_mfma_f32_16x16x32_bf16(w, x[0], acc[0][t], 0, 0, 0);
            acc[1][t] = __builtin_amdgcn_mfma_f32_16x16x32_bf16(w, x[1], acc[1][t], 0, 0, 0);
        }
    }
    #pragma unroll
    for (int f = 0; f < 2; f++) {
        int node = node0 + f * 16 + m16;
        if (node >= n) continue;
        #pragma unroll
        for (int t = 0; t < 16; t++) {
            int fbase = t * 16 + quad * 4;
            float4 bb = *(const float4*)(bias + fbase);
            ushort4 ov = { f2bf(acc[f][t][0] + bb.x), f2bf(acc[f][t][1] + bb.y),
                           f2bf(acc[f][t][2] + bb.z), f2bf(acc[f][t][3] + bb.w) };
            *(ushort4*)(out + (size_t)node * 256 + fbase) = ov;
        }
    }
}

// ---------------- per-node online-softmax aggregation (bf16 fs/fd) ----------------
// one wave per node; lane = (head = lane>>4, dims (lane&15)*4..+3); 4-edge unroll
__global__ __launch_bounds__(256) void k_agg(const unsigned short* __restrict__ fs,
                                             const unsigned short* __restrict__ fd,
                                             const int* __restrict__ offsets,
                                             const int* __restrict__ csr_src,
                                             const float* __restrict__ attn,
                                             unsigned short* __restrict__ hout, int n) {
    int wave = threadIdx.x >> 6;
    int lane = threadIdx.x & 63;
    int node = blockIdx.x * 4 + wave;
    if (node >= n) return;

    float4 at = *(const float4*)(attn + lane * 4);
    float atv[4] = {at.x, at.y, at.z, at.w};
    uint2 fdu = *(const uint2*)(fd + (size_t)node * 256 + lane * 4);
    float fdv[4];
    bf2f2(fdu.x, fdv[0], fdv[1]);
    bf2f2(fdu.y, fdv[2], fdv[3]);

    float m = -INFINITY, l = 0.f;
    float acc[4] = {0.f, 0.f, 0.f, 0.f};

    int beg = offsets[node], end = offsets[node + 1];
    int j = beg;
    for (; j + 4 <= end; j += 4) {
        int s0 = csr_src[j], s1 = csr_src[j + 1], s2 = csr_src[j + 2], s3 = csr_src[j + 3];
        uint2 g0 = *(const uint2*)(fs + (size_t)s0 * 256 + lane * 4);
        uint2 g1 = *(const uint2*)(fs + (size_t)s1 * 256 + lane * 4);
        uint2 g2 = *(const uint2*)(fs + (size_t)s2 * 256 + lane * 4);
        uint2 g3 = *(const uint2*)(fs + (size_t)s3 * 256 + lane * 4);
        float f0[4], f1[4], f2[4], f3[4];
        bf2f2(g0.x, f0[0], f0[1]); bf2f2(g0.y, f0[2], f0[3]);
        bf2f2(g1.x, f1[0], f1[1]); bf2f2(g1.y, f1[2], f1[3]);
        bf2f2(g2.x, f2[0], f2[1]); bf2f2(g2.y, f2[2], f2[3]);
        bf2f2(g3.x, f3[0], f3[1]); bf2f2(g3.y, f3[2], f3[3]);
        float p0 = 0.f, p1 = 0.f, p2 = 0.f, p3 = 0.f;
        #pragma unroll
        for (int k = 0; k < 4; k++) {
            p0 += atv[k] * lrelu(f0[k] + fdv[k]);
            p1 += atv[k] * lrelu(f1[k] + fdv[k]);
            p2 += atv[k] * lrelu(f2[k] + fdv[k]);
            p3 += atv[k] * lrelu(f3[k] + fdv[k]);
        }
        #pragma unroll
        for (int off = 1; off <= 8; off <<= 1) {
            p0 += __shfl_xor(p0, off, 64);
            p1 += __shfl_xor(p1, off, 64);
            p2 += __shfl_xor(p2, off, 64);
            p3 += __shfl_xor(p3, off, 64);
        }
        float nm = fmaxf(fmaxf(m, fmaxf(p0, p1)), fmaxf(p2, p3));
        float sc = __expf(m - nm);
        float w0 = __expf(p0 - nm), w1 = __expf(p1 - nm);
        float w2 = __expf(p2 - nm), w3 = __expf(p3 - nm);
        l = l * sc + w0 + w1 + w2 + w3;
        m = nm;
        #pragma unroll
        for (int k = 0; k < 4; k++)
            acc[k] = acc[k] * sc + w0 * f0[k] + w1 * f1[k] + w2 * f2[k] + w3 * f3[k];
    }
    for (; j < end; j++) {
        int s = csr_src[j];
        uint2 g = *(const uint2*)(fs + (size_t)s * 256 + lane * 4);
        float fv[4];
        bf2f2(g.x, fv[0], fv[1]); bf2f2(g.y, fv[2], fv[3]);
        float p = 0.f;
        #pragma unroll
        for (int k = 0; k < 4; k++) p += atv[k] * lrelu(fv[k] + fdv[k]);
        p += __shfl_xor(p, 1, 64);
        p += __shfl_xor(p, 2, 64);
        p += __shfl_xor(p, 4, 64);
        p += __shfl_xor(p, 8, 64);
        float nm = fmaxf(m, p);
        float sc = __expf(m - nm);
        float w = __expf(p - nm);
        l = l * sc + w;
        m = nm;
        #pragma unroll
        for (int k = 0; k < 4; k++) acc[k] = acc[k] * sc + w * fv[k];
    }
    float o[4];
    float inv = (l > 0.f) ? 1.f / l : 0.f;
    #pragma unroll
    for (int k = 0; k < 4; k++) o[k] = fast_tanh(acc[k] * inv);
    #pragma unroll
    for (int k = 0; k < 4; k++) {
        o[k] += __shfl_xor(o[k], 16, 64);
        o[k] += __shfl_xor(o[k], 32, 64);
    }
    if (lane < 16) {
        ushort4 ov = {f2bf(o[0]), f2bf(o[1]), f2bf(o[2]), f2bf(o[3])};
        *(ushort4*)(hout + (size_t)node * 64 + (lane & 15) * 4) = ov;
    }
}

// ---------------- graph readout: wave per 32 nodes, register accumulate ----------------
__global__ __launch_bounds__(256) void k_readout(const unsigned short* __restrict__ h,
                                                 const float* __restrict__ is_root,
                                                 const int* __restrict__ gid, float* __restrict__ hg, int n) {
    int wave = threadIdx.x >> 6, lane = threadIdx.x & 63;
    int start = blockIdx.x * 128 + wave * 32;
    if (start >= n) return;
    int stop = min(start + 32, n);
    float acc = 0.f;
    int cur = gid[start];
    for (int i = start; i < stop; i++) {
        int g = gid[i];
        if (g != cur) {
            atomicAdd(&hg[cur * 64 + lane], acc);
            acc = 0.f;
            cur = g;
        }
        acc += bf2f(h[(size_t)i * 64 + lane]) * is_root[i];
    }
    atomicAdd(&hg[cur * 64 + lane], acc);
}

__global__ __launch_bounds__(512) void k_out(const float* __restrict__ hg, const float* __restrict__ W_out,
                                             const float* __restrict__ b_out, float* __restrict__ out) {
    int t = threadIdx.x;
    if (t >= N_GRAPHS * 32) return;
    int b = t >> 5, c = t & 31;
    float a = b_out[c];
    #pragma unroll
    for (int d = 0; d < 64; d++) a += hg[b * 64 + d] * W_out[d * 32 + c];
    out[t] = a;
}

extern "C" void kernel_launch(void* const* d_in, const int* in_sizes, int n_in,
                              void* d_out, int out_size, void* d_ws, size_t ws_size,
                              hipStream_t stream) {
    const float* feat    = (const float*)d_in[0];
    const float* is_root = (const float*)d_in[1];
    const int*   src     = (const int*)d_in[2];
    const int*   dst     = (const int*)d_in[3];
    const int*   gid     = (const int*)d_in[4];
    const float* W_in    = (const float*)d_in[5];
    const float* b_in    = (const float*)d_in[6];
    const float* W_src   = (const float*)d_in[7];
    const float* b_src   = (const float*)d_in[8];
    const float* W_dst   = (const float*)d_in[9];
    const float* b_dst   = (const float*)d_in[10];
    const float* attn    = (const float*)d_in[11];
    const float* W_out   = (const float*)d_in[12];
    const float* b_out   = (const float*)d_in[13];
    float* out = (float*)d_out;

    char* ws = (char*)d_ws;
    size_t off = 0;
    auto take = [&](size_t bytes) -> char* {
        char* p = ws + off;
        off = (off + bytes + 255) & ~(size_t)255;
        return p;
    };
    unsigned short* fs    = (unsigned short*)take((size_t)N_NODES * 256 * 2);
    unsigned short* fd    = (unsigned short*)take((size_t)N_NODES * 256 * 2);
    unsigned short* h0    = (unsigned short*)take((size_t)N_NODES * 64 * 2);
    unsigned short* hA    = (unsigned short*)take((size_t)N_NODES * 64 * 2);
    unsigned short* hB    = (unsigned short*)take((size_t)N_NODES * 64 * 2);
    unsigned short* Wpack = (unsigned short*)take((size_t)2 * 32768 * 2);
    float* hg             = (float*)take((size_t)N_GRAPHS * 64 * 4);
    int*   offsets        = (int*)take((size_t)(N_NODES + 1) * 4);
    int*   cursor         = (int*)take((size_t)N_NODES * 4);
    int*   csr_src        = (int*)take((size_t)N_EDGES * 4);
    int*   bsums          = (int*)take((size_t)128 * 4);

    const int n = N_NODES, e = N_EDGES;
    const int nb = (n + 511) / 512;  // 98
    dim3 b256(256);

    k_init<<<dim3((n + 255) / 256), b256, 0, stream>>>(cursor, hg);
    k_h0_pack<<<dim3(12756), b256, 0, stream>>>(feat, W_in, b_in, h0, W_src, W_dst, Wpack);

    // CSR build
    k_hist<<<dim3((e + 255) / 256), b256, 0, stream>>>(dst, cursor, e);
    k_scan_local<<<dim3(nb), dim3(512), 0, stream>>>(cursor, offsets, bsums, n);
    k_scan_sums<<<dim3(1), dim3(128), 0, stream>>>(bsums, nb);
    k_scan_add<<<dim3(nb), dim3(512), 0, stream>>>(offsets, bsums, n);
    k_fill<<<dim3((e + 255) / 256), b256, 0, stream>>>(src, dst, offsets, cursor, csr_src, e);

    // 4 GATv2 layers
    const unsigned short* hin = h0;
    unsigned short* houts[4] = { hA, hB, hA, hB };
    for (int layer = 0; layer < 4; layer++) {
        k_gemm<<<dim3((n + 127) / 128, 2), b256, 0, stream>>>(hin, h0, Wpack, b_src, b_dst, fs, fd, n);
        k_agg<<<dim3((n + 3) / 4), b256, 0, stream>>>(fs, fd, offsets, csr_src, attn, houts[layer], n);
        hin = houts[layer];
    }

    // readout
    k_readout<<<dim3((n + 127) / 128), b256, 0, stream>>>(hB, is_root, gid, hg, n);
    k_out<<<dim3(1), dim3(512), 0, stream>>>(hg, W_out, b_out, out);
}

// Round 6
// 495.758 us; speedup vs baseline: 2.6883x; 1.0582x over previous
//
#include <hip/hip_runtime.h>
#include <math.h>

#define N_NODES 50000
#define N_EDGES 400000
#define N_GRAPHS 16
#define HEADS 4
#define NEG_SLOPE 0.2f

typedef __attribute__((ext_vector_type(8))) short short8;
typedef __attribute__((ext_vector_type(4))) float floatx4;

__device__ __forceinline__ unsigned short f2bf(float x) {
    union { float f; unsigned int u; } v; v.f = x;
    unsigned int r = v.u + 0x7fffu + ((v.u >> 16) & 1u);
    return (unsigned short)(r >> 16);
}
__device__ __forceinline__ float bf2f(unsigned short b) {
    union { unsigned int u; float f; } v; v.u = ((unsigned int)b) << 16;
    return v.f;
}
// two packed bf16 -> two f32 in 2 VALU ops
__device__ __forceinline__ void bf2f2(unsigned int u, float& lo, float& hi) {
    union { unsigned int i; float f; } a, b;
    a.i = u << 16; b.i = u & 0xffff0000u;
    lo = a.f; hi = b.f;
}
__device__ __forceinline__ float fast_tanh(float x) {
    float e = __expf(2.f * x);
    return 1.f - 2.f / (e + 1.f);
}
__device__ __forceinline__ float lrelu(float e) {
    return fmaxf(e, NEG_SLOPE * e);
}

// ---------------- init: zero cursor + hg ----------------
__global__ __launch_bounds__(256) void k_init(int* __restrict__ cursor, float* __restrict__ hg) {
    int i = blockIdx.x * 256 + threadIdx.x;
    if (i < N_NODES) cursor[i] = 0;
    if (i < N_GRAPHS * 64) hg[i] = 0.f;
}

// ---------------- fused h0 + weight pack ----------------
// Wpack layout (A-frag, 16x16x32): Wpack[mat][(t*4+q)*64+lane][j] = W[q*32+(lane>>4)*8+j][t*16+(lane&15)]
__global__ __launch_bounds__(256) void k_h0_pack(const float* __restrict__ feat,
                                                 const float* __restrict__ W_in,
                                                 const float* __restrict__ b_in,
                                                 unsigned short* __restrict__ h0,
                                                 const float* __restrict__ Wsrc,
                                                 const float* __restrict__ Wdst,
                                                 unsigned short* __restrict__ Wpack) {
    int bid = blockIdx.x;
    if (bid < 12500) {
        int idx = bid * 256 + threadIdx.x;
        int node = idx >> 6, d = idx & 63;
        float acc = b_in[d];
        #pragma unroll
        for (int k = 0; k < 16; k++) acc += feat[node * 16 + k] * W_in[k * 64 + d];
        h0[idx] = f2bf(acc);
    } else {
        int pb = bid - 12500;                       // 0..255
        int mat = pb >> 7;                          // 0/1
        int idx = (pb & 127) * 256 + threadIdx.x;   // 0..32767
        const float* W = mat ? Wdst : Wsrc;
        int j = idx & 7;
        int lane = (idx >> 3) & 63;
        int q = (idx >> 9) & 3;
        int t = (idx >> 11) & 15;
        int col = t * 16 + (lane & 15);
        int k = q * 32 + (lane >> 4) * 8 + j;
        Wpack[mat * 32768 + idx] = f2bf(W[k * 256 + col]);
    }
}

// ---------------- CSR build ----------------
__global__ __launch_bounds__(256) void k_hist(const int* __restrict__ dst, int* __restrict__ indeg, int e) {
    int i = blockIdx.x * 256 + threadIdx.x;
    if (i < e) atomicAdd(&indeg[dst[i]], 1);
}

__global__ __launch_bounds__(512) void k_scan_local(int* __restrict__ indeg,
                                                    int* __restrict__ offsets,
                                                    int* __restrict__ bsums, int n) {
    __shared__ int tmp[512];
    int t = threadIdx.x;
    int idx = blockIdx.x * 512 + t;
    int v = (idx < n) ? indeg[idx] : 0;
    tmp[t] = v;
    __syncthreads();
    #pragma unroll
    for (int off = 1; off < 512; off <<= 1) {
        int add = (t >= off) ? tmp[t - off] : 0;
        __syncthreads();
        tmp[t] += add;
        __syncthreads();
    }
    if (idx < n) { offsets[idx] = tmp[t] - v; indeg[idx] = 0; }
    if (t == 511) bsums[blockIdx.x] = tmp[511];
}

__global__ __launch_bounds__(128) void k_scan_sums(int* __restrict__ bsums, int nb) {
    __shared__ int tmp[128];
    int t = threadIdx.x;
    int v = (t < nb) ? bsums[t] : 0;
    tmp[t] = v;
    __syncthreads();
    #pragma unroll
    for (int off = 1; off < 128; off <<= 1) {
        int add = (t >= off) ? tmp[t - off] : 0;
        __syncthreads();
        tmp[t] += add;
        __syncthreads();
    }
    if (t < nb) bsums[t] = tmp[t] - v;
}

__global__ __launch_bounds__(512) void k_scan_add(int* __restrict__ offsets,
                                                  const int* __restrict__ bsums, int n) {
    int idx = blockIdx.x * 512 + threadIdx.x;
    if (idx < n) offsets[idx] += bsums[blockIdx.x];
    if (idx == 0) offsets[n] = N_EDGES;
}

__global__ __launch_bounds__(256) void k_fill(const int* __restrict__ src, const int* __restrict__ dst,
                                              const int* __restrict__ offsets, int* __restrict__ cursor,
                                              int* __restrict__ csr_src, int e) {
    int i = blockIdx.x * 256 + threadIdx.x;
    if (i >= e) return;
    int d = dst[i];
    int slot = offsets[d] + atomicAdd(&cursor[d], 1);
    csr_src[slot] = src[i];
}

// ---------------- fs/fd = [h|h0] @ W + b  via MFMA (A=W, B=X^T) ----------------
// wave = 16 nodes x 128 feats (acc[8] => 32 VGPRs). Block 256 = 4 waves =
// 2 node-groups x 2 feature-halves = 32 nodes x 256 feats.
// grid.x = ceil(n/32), grid.y = 2 (mat)
__global__ __launch_bounds__(256) void k_gemm(const unsigned short* __restrict__ h,
                                              const unsigned short* __restrict__ h0,
                                              const unsigned short* __restrict__ Wpack,
                                              const float* __restrict__ bsrc,
                                              const float* __restrict__ bdst,
                                              unsigned short* __restrict__ fs,
                                              unsigned short* __restrict__ fd, int n) {
    int mat = blockIdx.y;
    const unsigned short* Wp = Wpack + mat * 32768;
    const float* bias = mat ? bdst : bsrc;
    unsigned short* out = mat ? fd : fs;
    int wave = threadIdx.x >> 6, lane = threadIdx.x & 63;
    int quad = lane >> 4, m16 = lane & 15;
    int fhalf = wave & 1;           // feature half: 0 -> feats 0..127, 1 -> 128..255
    int ngrp = wave >> 1;           // node group within block
    int node0 = blockIdx.x * 32 + ngrp * 16;

    floatx4 acc[8];
    #pragma unroll
    for (int t = 0; t < 8; t++) acc[t] = (floatx4){0.f, 0.f, 0.f, 0.f};

    int r = node0 + m16;
    if (r > n - 1) r = n - 1;

    #pragma unroll
    for (int q = 0; q < 4; q++) {
        int kk = q * 32 + quad * 8;
        const unsigned short* base = (kk < 64) ? (h + (size_t)r * 64 + kk)
                                               : (h0 + (size_t)r * 64 + (kk - 64));
        short8 x = *(const short8*)base;
        #pragma unroll
        for (int t = 0; t < 8; t++) {
            int tt = fhalf * 8 + t;
            short8 w = *(const short8*)(Wp + ((size_t)(tt * 4 + q) * 64 + lane) * 8);
            acc[t] = __builtin_amdgcn_mfma_f32_16x16x32_bf16(w, x, acc[t], 0, 0, 0);
        }
    }
    int node = node0 + m16;
    if (node < n) {
        #pragma unroll
        for (int t = 0; t < 8; t++) {
            int fbase = (fhalf * 8 + t) * 16 + quad * 4;
            float4 bb = *(const float4*)(bias + fbase);
            ushort4 ov = { f2bf(acc[t][0] + bb.x), f2bf(acc[t][1] + bb.y),
                           f2bf(acc[t][2] + bb.z), f2bf(acc[t][3] + bb.w) };
            *(ushort4*)(out + (size_t)node * 256 + fbase) = ov;
        }
    }
}

// ---------------- per-node aggregation: 2 edge-slots/wave, 8 dims/lane ----------------
// lane = (slot = lane>>5, head = (lane>>3)&3, dg = lane&7 -> dims dg*8..+7)
// direct exp (no online max: |logit| analytically << 88; clamped at 80)
__global__ __launch_bounds__(256) void k_agg(const unsigned short* __restrict__ fs,
                                             const unsigned short* __restrict__ fd,
                                             const int* __restrict__ offsets,
                                             const int* __restrict__ csr_src,
                                             const float* __restrict__ attn,
                                             unsigned short* __restrict__ hout, int n) {
    int wave = threadIdx.x >> 6;
    int lane = threadIdx.x & 63;
    int node = blockIdx.x * 4 + wave;
    if (node >= n) return;
    int slot = lane >> 5;
    int foff = ((lane >> 3) & 3) * 64 + (lane & 7) * 8;   // head*64 + dg*8

    float at[8];
    {
        float4 a0 = *(const float4*)(attn + foff);
        float4 a1 = *(const float4*)(attn + foff + 4);
        at[0] = a0.x; at[1] = a0.y; at[2] = a0.z; at[3] = a0.w;
        at[4] = a1.x; at[5] = a1.y; at[6] = a1.z; at[7] = a1.w;
    }
    float fdv[8];
    {
        uint4 u = *(const uint4*)(fd + (size_t)node * 256 + foff);
        bf2f2(u.x, fdv[0], fdv[1]); bf2f2(u.y, fdv[2], fdv[3]);
        bf2f2(u.z, fdv[4], fdv[5]); bf2f2(u.w, fdv[6], fdv[7]);
    }

    float l = 0.f;
    float acc[8] = {0.f, 0.f, 0.f, 0.f, 0.f, 0.f, 0.f, 0.f};

    int beg = offsets[node], end = offsets[node + 1];
    for (int j = beg; j < end; j += 2) {
        int ej = j + slot;
        bool valid = ej < end;
        int s = csr_src[valid ? ej : j];
        uint4 g = *(const uint4*)(fs + (size_t)s * 256 + foff);
        float fv[8];
        bf2f2(g.x, fv[0], fv[1]); bf2f2(g.y, fv[2], fv[3]);
        bf2f2(g.z, fv[4], fv[5]); bf2f2(g.w, fv[6], fv[7]);
        float p = 0.f;
        #pragma unroll
        for (int k = 0; k < 8; k++) p += at[k] * lrelu(fv[k] + fdv[k]);
        p += __shfl_xor(p, 1, 64);
        p += __shfl_xor(p, 2, 64);
        p += __shfl_xor(p, 4, 64);
        float w = valid ? __expf(fminf(p, 80.f)) : 0.f;
        l += w;
        #pragma unroll
        for (int k = 0; k < 8; k++) acc[k] += w * fv[k];
    }
    // merge the two edge-slots
    l += __shfl_xor(l, 32, 64);
    #pragma unroll
    for (int k = 0; k < 8; k++) acc[k] += __shfl_xor(acc[k], 32, 64);

    float inv = (l > 0.f) ? 1.f / l : 0.f;
    float o[8];
    #pragma unroll
    for (int k = 0; k < 8; k++) o[k] = fast_tanh(acc[k] * inv);
    // sum over heads (lane bits 3,4)
    #pragma unroll
    for (int k = 0; k < 8; k++) {
        o[k] += __shfl_xor(o[k], 8, 64);
        o[k] += __shfl_xor(o[k], 16, 64);
    }
    if (lane < 8) {
        ushort4 lo = {f2bf(o[0]), f2bf(o[1]), f2bf(o[2]), f2bf(o[3])};
        ushort4 hi = {f2bf(o[4]), f2bf(o[5]), f2bf(o[6]), f2bf(o[7])};
        unsigned short* dstp = hout + (size_t)node * 64 + (lane & 7) * 8;
        *(ushort4*)dstp = lo;
        *(ushort4*)(dstp + 4) = hi;
    }
}

// ---------------- graph readout: wave per 32 nodes, register accumulate ----------------
__global__ __launch_bounds__(256) void k_readout(const unsigned short* __restrict__ h,
                                                 const float* __restrict__ is_root,
                                                 const int* __restrict__ gid, float* __restrict__ hg, int n) {
    int wave = threadIdx.x >> 6, lane = threadIdx.x & 63;
    int start = blockIdx.x * 128 + wave * 32;
    if (start >= n) return;
    int stop = min(start + 32, n);
    float acc = 0.f;
    int cur = gid[start];
    for (int i = start; i < stop; i++) {
        int g = gid[i];
        if (g != cur) {
            atomicAdd(&hg[cur * 64 + lane], acc);
            acc = 0.f;
            cur = g;
        }
        acc += bf2f(h[(size_t)i * 64 + lane]) * is_root[i];
    }
    atomicAdd(&hg[cur * 64 + lane], acc);
}

__global__ __launch_bounds__(512) void k_out(const float* __restrict__ hg, const float* __restrict__ W_out,
                                             const float* __restrict__ b_out, float* __restrict__ out) {
    int t = threadIdx.x;
    if (t >= N_GRAPHS * 32) return;
    int b = t >> 5, c = t & 31;
    float a = b_out[c];
    #pragma unroll
    for (int d = 0; d < 64; d++) a += hg[b * 64 + d] * W_out[d * 32 + c];
    out[t] = a;
}

extern "C" void kernel_launch(void* const* d_in, const int* in_sizes, int n_in,
                              void* d_out, int out_size, void* d_ws, size_t ws_size,
                              hipStream_t stream) {
    const float* feat    = (const float*)d_in[0];
    const float* is_root = (const float*)d_in[1];
    const int*   src     = (const int*)d_in[2];
    const int*   dst     = (const int*)d_in[3];
    const int*   gid     = (const int*)d_in[4];
    const float* W_in    = (const float*)d_in[5];
    const float* b_in    = (const float*)d_in[6];
    const float* W_src   = (const float*)d_in[7];
    const float* b_src   = (const float*)d_in[8];
    const float* W_dst   = (const float*)d_in[9];
    const float* b_dst   = (const float*)d_in[10];
    const float* attn    = (const float*)d_in[11];
    const float* W_out   = (const float*)d_in[12];
    const float* b_out   = (const float*)d_in[13];
    float* out = (float*)d_out;

    char* ws = (char*)d_ws;
    size_t off = 0;
    auto take = [&](size_t bytes) -> char* {
        char* p = ws + off;
        off = (off + bytes + 255) & ~(size_t)255;
        return p;
    };
    unsigned short* fs    = (unsigned short*)take((size_t)N_NODES * 256 * 2);
    unsigned short* fd    = (unsigned short*)take((size_t)N_NODES * 256 * 2);
    unsigned short* h0    = (unsigned short*)take((size_t)N_NODES * 64 * 2);
    unsigned short* hA    = (unsigned short*)take((size_t)N_NODES * 64 * 2);
    unsigned short* hB    = (unsigned short*)take((size_t)N_NODES * 64 * 2);
    unsigned short* Wpack = (unsigned short*)take((size_t)2 * 32768 * 2);
    float* hg             = (float*)take((size_t)N_GRAPHS * 64 * 4);
    int*   offsets        = (int*)take((size_t)(N_NODES + 1) * 4);
    int*   cursor         = (int*)take((size_t)N_NODES * 4);
    int*   csr_src        = (int*)take((size_t)N_EDGES * 4);
    int*   bsums          = (int*)take((size_t)128 * 4);

    const int n = N_NODES, e = N_EDGES;
    const int nb = (n + 511) / 512;  // 98
    dim3 b256(256);

    k_init<<<dim3((n + 255) / 256), b256, 0, stream>>>(cursor, hg);
    k_h0_pack<<<dim3(12756), b256, 0, stream>>>(feat, W_in, b_in, h0, W_src, W_dst, Wpack);

    // CSR build
    k_hist<<<dim3((e + 255) / 256), b256, 0, stream>>>(dst, cursor, e);
    k_scan_local<<<dim3(nb), dim3(512), 0, stream>>>(cursor, offsets, bsums, n);
    k_scan_sums<<<dim3(1), dim3(128), 0, stream>>>(bsums, nb);
    k_scan_add<<<dim3(nb), dim3(512), 0, stream>>>(offsets, bsums, n);
    k_fill<<<dim3((e + 255) / 256), b256, 0, stream>>>(src, dst, offsets, cursor, csr_src, e);

    // 4 GATv2 layers
    const unsigned short* hin = h0;
    unsigned short* houts[4] = { hA, hB, hA, hB };
    for (int layer = 0; layer < 4; layer++) {
        k_gemm<<<dim3((n + 31) / 32, 2), b256, 0, stream>>>(hin, h0, Wpack, b_src, b_dst, fs, fd, n);
        k_agg<<<dim3((n + 3) / 4), b256, 0, stream>>>(fs, fd, offsets, csr_src, attn, houts[layer], n);
        hin = houts[layer];
    }

    // readout
    k_readout<<<dim3((n + 127) / 128), b256, 0, stream>>>(hB, is_root, gid, hg, n);
    k_out<<<dim3(1), dim3(512), 0, stream>>>(hg, W_out, b_out, out);
}

// Round 7
// 472.332 us; speedup vs baseline: 2.8216x; 1.0496x over previous
//
#include <hip/hip_runtime.h>
#include <math.h>

#define N_NODES 50000
#define N_EDGES 400000
#define N_GRAPHS 16
#define HEADS 4
#define NEG_SLOPE 0.2f

typedef __attribute__((ext_vector_type(8))) short short8;
typedef __attribute__((ext_vector_type(4))) float floatx4;
typedef _Float16 half_t;
typedef _Float16 half2_t __attribute__((ext_vector_type(2)));
typedef _Float16 half4_t __attribute__((ext_vector_type(4)));

__device__ __forceinline__ unsigned short f2bf(float x) {
    union { float f; unsigned int u; } v; v.f = x;
    unsigned int r = v.u + 0x7fffu + ((v.u >> 16) & 1u);
    return (unsigned short)(r >> 16);
}
__device__ __forceinline__ float bf2f(unsigned short b) {
    union { unsigned int u; float f; } v; v.u = ((unsigned int)b) << 16;
    return v.f;
}
__device__ __forceinline__ half2_t u2h2(unsigned int u) {
    union { unsigned int i; half2_t h; } v; v.i = u;
    return v.h;
}
__device__ __forceinline__ float fast_tanh(float x) {
    float e = __expf(2.f * x);
    return 1.f - 2.f / (e + 1.f);
}
// packed leaky-relu: max(e, 0.2*e) on 2 halves
__device__ __forceinline__ half2_t lrelu2(half2_t e) {
    half2_t s = e * (half2_t){(half_t)NEG_SLOPE, (half_t)NEG_SLOPE};
    return __builtin_elementwise_max(e, s);
}
__device__ __forceinline__ float dot2acc(half2_t a, half2_t b, float c) {
#if __has_builtin(__builtin_amdgcn_fdot2)
    return __builtin_amdgcn_fdot2(a, b, c, false);
#else
    return c + (float)a[0] * (float)b[0] + (float)a[1] * (float)b[1];
#endif
}

// ---------------- init: zero cursor + hg ----------------
__global__ __launch_bounds__(256) void k_init(int* __restrict__ cursor, float* __restrict__ hg) {
    int i = blockIdx.x * 256 + threadIdx.x;
    if (i < N_NODES) cursor[i] = 0;
    if (i < N_GRAPHS * 64) hg[i] = 0.f;
}

// ---------------- fused h0 + weight pack ----------------
// Wpack layout (A-frag, 16x16x32): Wpack[mat][(t*4+q)*64+lane][j] = W[q*32+(lane>>4)*8+j][t*16+(lane&15)]
__global__ __launch_bounds__(256) void k_h0_pack(const float* __restrict__ feat,
                                                 const float* __restrict__ W_in,
                                                 const float* __restrict__ b_in,
                                                 unsigned short* __restrict__ h0,
                                                 const float* __restrict__ Wsrc,
                                                 const float* __restrict__ Wdst,
                                                 unsigned short* __restrict__ Wpack) {
    int bid = blockIdx.x;
    if (bid < 12500) {
        int idx = bid * 256 + threadIdx.x;
        int node = idx >> 6, d = idx & 63;
        float acc = b_in[d];
        #pragma unroll
        for (int k = 0; k < 16; k++) acc += feat[node * 16 + k] * W_in[k * 64 + d];
        h0[idx] = f2bf(acc);
    } else {
        int pb = bid - 12500;                       // 0..255
        int mat = pb >> 7;                          // 0/1
        int idx = (pb & 127) * 256 + threadIdx.x;   // 0..32767
        const float* W = mat ? Wdst : Wsrc;
        int j = idx & 7;
        int lane = (idx >> 3) & 63;
        int q = (idx >> 9) & 3;
        int t = (idx >> 11) & 15;
        int col = t * 16 + (lane & 15);
        int k = q * 32 + (lane >> 4) * 8 + j;
        Wpack[mat * 32768 + idx] = f2bf(W[k * 256 + col]);
    }
}

// ---------------- CSR build ----------------
__global__ __launch_bounds__(256) void k_hist(const int* __restrict__ dst, int* __restrict__ indeg, int e) {
    int i = blockIdx.x * 256 + threadIdx.x;
    if (i < e) atomicAdd(&indeg[dst[i]], 1);
}

__global__ __launch_bounds__(512) void k_scan_local(int* __restrict__ indeg,
                                                    int* __restrict__ offsets,
                                                    int* __restrict__ bsums, int n) {
    __shared__ int tmp[512];
    int t = threadIdx.x;
    int idx = blockIdx.x * 512 + t;
    int v = (idx < n) ? indeg[idx] : 0;
    tmp[t] = v;
    __syncthreads();
    #pragma unroll
    for (int off = 1; off < 512; off <<= 1) {
        int add = (t >= off) ? tmp[t - off] : 0;
        __syncthreads();
        tmp[t] += add;
        __syncthreads();
    }
    if (idx < n) { offsets[idx] = tmp[t] - v; indeg[idx] = 0; }
    if (t == 511) bsums[blockIdx.x] = tmp[511];
}

__global__ __launch_bounds__(128) void k_scan_sums(int* __restrict__ bsums, int nb) {
    __shared__ int tmp[128];
    int t = threadIdx.x;
    int v = (t < nb) ? bsums[t] : 0;
    tmp[t] = v;
    __syncthreads();
    #pragma unroll
    for (int off = 1; off < 128; off <<= 1) {
        int add = (t >= off) ? tmp[t - off] : 0;
        __syncthreads();
        tmp[t] += add;
        __syncthreads();
    }
    if (t < nb) bsums[t] = tmp[t] - v;
}

__global__ __launch_bounds__(512) void k_scan_add(int* __restrict__ offsets,
                                                  const int* __restrict__ bsums, int n) {
    int idx = blockIdx.x * 512 + threadIdx.x;
    if (idx < n) offsets[idx] += bsums[blockIdx.x];
    if (idx == 0) offsets[n] = N_EDGES;
}

__global__ __launch_bounds__(256) void k_fill(const int* __restrict__ src, const int* __restrict__ dst,
                                              const int* __restrict__ offsets, int* __restrict__ cursor,
                                              int* __restrict__ csr_src, int e) {
    int i = blockIdx.x * 256 + threadIdx.x;
    if (i >= e) return;
    int d = dst[i];
    int slot = offsets[d] + atomicAdd(&cursor[d], 1);
    csr_src[slot] = src[i];
}

// ---------------- fs/fd = [h|h0] @ W + b  via MFMA (A=W, B=X^T), f16 out ----------------
// wave = 16 nodes x 128 feats. Block 256 = 4 waves. grid.x = ceil(n/32), grid.y = 2 (mat)
__global__ __launch_bounds__(256) void k_gemm(const unsigned short* __restrict__ h,
                                              const unsigned short* __restrict__ h0,
                                              const unsigned short* __restrict__ Wpack,
                                              const float* __restrict__ bsrc,
                                              const float* __restrict__ bdst,
                                              half_t* __restrict__ fs,
                                              half_t* __restrict__ fd, int n) {
    int mat = blockIdx.y;
    const unsigned short* Wp = Wpack + mat * 32768;
    const float* bias = mat ? bdst : bsrc;
    half_t* out = mat ? fd : fs;
    int wave = threadIdx.x >> 6, lane = threadIdx.x & 63;
    int quad = lane >> 4, m16 = lane & 15;
    int fhalf = wave & 1;
    int ngrp = wave >> 1;
    int node0 = blockIdx.x * 32 + ngrp * 16;

    floatx4 acc[8];
    #pragma unroll
    for (int t = 0; t < 8; t++) acc[t] = (floatx4){0.f, 0.f, 0.f, 0.f};

    int r = node0 + m16;
    if (r > n - 1) r = n - 1;

    #pragma unroll
    for (int q = 0; q < 4; q++) {
        int kk = q * 32 + quad * 8;
        const unsigned short* base = (kk < 64) ? (h + (size_t)r * 64 + kk)
                                               : (h0 + (size_t)r * 64 + (kk - 64));
        short8 x = *(const short8*)base;
        #pragma unroll
        for (int t = 0; t < 8; t++) {
            int tt = fhalf * 8 + t;
            short8 w = *(const short8*)(Wp + ((size_t)(tt * 4 + q) * 64 + lane) * 8);
            acc[t] = __builtin_amdgcn_mfma_f32_16x16x32_bf16(w, x, acc[t], 0, 0, 0);
        }
    }
    int node = node0 + m16;
    if (node < n) {
        #pragma unroll
        for (int t = 0; t < 8; t++) {
            int fbase = (fhalf * 8 + t) * 16 + quad * 4;
            float4 bb = *(const float4*)(bias + fbase);
            half4_t ov = { (half_t)(acc[t][0] + bb.x), (half_t)(acc[t][1] + bb.y),
                           (half_t)(acc[t][2] + bb.z), (half_t)(acc[t][3] + bb.w) };
            *(half4_t*)(out + (size_t)node * 256 + fbase) = ov;
        }
    }
}

// ---------------- per-node aggregation: packed-f16 math ----------------
// lane = (slot = lane>>5, head = (lane>>3)&3, dg = lane&7 -> dims dg*8..+7)
// 2 slots x 2-edge unroll = 4 edges/iter; tails masked with w=0.
__global__ __launch_bounds__(256) void k_agg(const half_t* __restrict__ fs,
                                             const half_t* __restrict__ fd,
                                             const int* __restrict__ offsets,
                                             const int* __restrict__ csr_src,
                                             const float* __restrict__ attn,
                                             unsigned short* __restrict__ hout, int n) {
    int wave = threadIdx.x >> 6;
    int lane = threadIdx.x & 63;
    int node = blockIdx.x * 4 + wave;
    if (node >= n) return;
    int slot = lane >> 5;
    int foff = ((lane >> 3) & 3) * 64 + (lane & 7) * 8;   // head*64 + dg*8

    half2_t at2[4];
    {
        float4 a0 = *(const float4*)(attn + foff);
        float4 a1 = *(const float4*)(attn + foff + 4);
        at2[0] = (half2_t){(half_t)a0.x, (half_t)a0.y};
        at2[1] = (half2_t){(half_t)a0.z, (half_t)a0.w};
        at2[2] = (half2_t){(half_t)a1.x, (half_t)a1.y};
        at2[3] = (half2_t){(half_t)a1.z, (half_t)a1.w};
    }
    half2_t fd2[4];
    {
        uint4 u = *(const uint4*)(fd + (size_t)node * 256 + foff);
        fd2[0] = u2h2(u.x); fd2[1] = u2h2(u.y); fd2[2] = u2h2(u.z); fd2[3] = u2h2(u.w);
    }

    float l = 0.f;
    half2_t zero2 = {(half_t)0.f, (half_t)0.f};
    half2_t acc2[4] = {zero2, zero2, zero2, zero2};

    int beg = offsets[node], end = offsets[node + 1];
    for (int j = beg; j < end; j += 4) {
        int e0 = j + slot, e1 = j + 2 + slot;
        bool v0 = e0 < end, v1 = e1 < end;
        int s0 = csr_src[v0 ? e0 : beg];
        int s1 = csr_src[v1 ? e1 : beg];
        uint4 g0 = *(const uint4*)(fs + (size_t)s0 * 256 + foff);
        uint4 g1 = *(const uint4*)(fs + (size_t)s1 * 256 + foff);
        half2_t f0[4] = {u2h2(g0.x), u2h2(g0.y), u2h2(g0.z), u2h2(g0.w)};
        half2_t f1[4] = {u2h2(g1.x), u2h2(g1.y), u2h2(g1.z), u2h2(g1.w)};
        float p0 = 0.f, p1 = 0.f;
        #pragma unroll
        for (int k = 0; k < 4; k++) {
            p0 = dot2acc(at2[k], lrelu2(f0[k] + fd2[k]), p0);
            p1 = dot2acc(at2[k], lrelu2(f1[k] + fd2[k]), p1);
        }
        p0 += __shfl_xor(p0, 1, 64); p1 += __shfl_xor(p1, 1, 64);
        p0 += __shfl_xor(p0, 2, 64); p1 += __shfl_xor(p1, 2, 64);
        p0 += __shfl_xor(p0, 4, 64); p1 += __shfl_xor(p1, 4, 64);
        float w0 = v0 ? __expf(fminf(p0, 80.f)) : 0.f;
        float w1 = v1 ? __expf(fminf(p1, 80.f)) : 0.f;
        l += w0 + w1;
        half_t hw0 = (half_t)w0, hw1 = (half_t)w1;
        half2_t w02 = {hw0, hw0}, w12 = {hw1, hw1};
        #pragma unroll
        for (int k = 0; k < 4; k++) {
            acc2[k] += w02 * f0[k];
            acc2[k] += w12 * f1[k];
        }
    }
    // merge the two edge-slots (xor 32)
    l += __shfl_xor(l, 32, 64);
    #pragma unroll
    for (int k = 0; k < 4; k++) {
        float t = __builtin_bit_cast(float, acc2[k]);
        t = __shfl_xor(t, 32, 64);
        acc2[k] += __builtin_bit_cast(half2_t, t);
    }

    float inv = (l > 0.f) ? 1.f / l : 0.f;
    float o[8];
    #pragma unroll
    for (int k = 0; k < 4; k++) {
        o[2 * k]     = fast_tanh((float)acc2[k][0] * inv);
        o[2 * k + 1] = fast_tanh((float)acc2[k][1] * inv);
    }
    // sum over heads (lane bits 3,4)
    #pragma unroll
    for (int k = 0; k < 8; k++) {
        o[k] += __shfl_xor(o[k], 8, 64);
        o[k] += __shfl_xor(o[k], 16, 64);
    }
    if (lane < 8) {
        ushort4 lo = {f2bf(o[0]), f2bf(o[1]), f2bf(o[2]), f2bf(o[3])};
        ushort4 hi = {f2bf(o[4]), f2bf(o[5]), f2bf(o[6]), f2bf(o[7])};
        unsigned short* dstp = hout + (size_t)node * 64 + (lane & 7) * 8;
        *(ushort4*)dstp = lo;
        *(ushort4*)(dstp + 4) = hi;
    }
}

// ---------------- graph readout: wave per 32 nodes, register accumulate ----------------
__global__ __launch_bounds__(256) void k_readout(const unsigned short* __restrict__ h,
                                                 const float* __restrict__ is_root,
                                                 const int* __restrict__ gid, float* __restrict__ hg, int n) {
    int wave = threadIdx.x >> 6, lane = threadIdx.x & 63;
    int start = blockIdx.x * 128 + wave * 32;
    if (start >= n) return;
    int stop = min(start + 32, n);
    float acc = 0.f;
    int cur = gid[start];
    for (int i = start; i < stop; i++) {
        int g = gid[i];
        if (g != cur) {
            atomicAdd(&hg[cur * 64 + lane], acc);
            acc = 0.f;
            cur = g;
        }
        acc += bf2f(h[(size_t)i * 64 + lane]) * is_root[i];
    }
    atomicAdd(&hg[cur * 64 + lane], acc);
}

__global__ __launch_bounds__(512) void k_out(const float* __restrict__ hg, const float* __restrict__ W_out,
                                             const float* __restrict__ b_out, float* __restrict__ out) {
    int t = threadIdx.x;
    if (t >= N_GRAPHS * 32) return;
    int b = t >> 5, c = t & 31;
    float a = b_out[c];
    #pragma unroll
    for (int d = 0; d < 64; d++) a += hg[b * 64 + d] * W_out[d * 32 + c];
    out[t] = a;
}

extern "C" void kernel_launch(void* const* d_in, const int* in_sizes, int n_in,
                              void* d_out, int out_size, void* d_ws, size_t ws_size,
                              hipStream_t stream) {
    const float* feat    = (const float*)d_in[0];
    const float* is_root = (const float*)d_in[1];
    const int*   src     = (const int*)d_in[2];
    const int*   dst     = (const int*)d_in[3];
    const int*   gid     = (const int*)d_in[4];
    const float* W_in    = (const float*)d_in[5];
    const float* b_in    = (const float*)d_in[6];
    const float* W_src   = (const float*)d_in[7];
    const float* b_src   = (const float*)d_in[8];
    const float* W_dst   = (const float*)d_in[9];
    const float* b_dst   = (const float*)d_in[10];
    const float* attn    = (const float*)d_in[11];
    const float* W_out   = (const float*)d_in[12];
    const float* b_out   = (const float*)d_in[13];
    float* out = (float*)d_out;

    char* ws = (char*)d_ws;
    size_t off = 0;
    auto take = [&](size_t bytes) -> char* {
        char* p = ws + off;
        off = (off + bytes + 255) & ~(size_t)255;
        return p;
    };
    half_t* fs            = (half_t*)take((size_t)N_NODES * 256 * 2);
    half_t* fd            = (half_t*)take((size_t)N_NODES * 256 * 2);
    unsigned short* h0    = (unsigned short*)take((size_t)N_NODES * 64 * 2);
    unsigned short* hA    = (unsigned short*)take((size_t)N_NODES * 64 * 2);
    unsigned short* hB    = (unsigned short*)take((size_t)N_NODES * 64 * 2);
    unsigned short* Wpack = (unsigned short*)take((size_t)2 * 32768 * 2);
    float* hg             = (float*)take((size_t)N_GRAPHS * 64 * 4);
    int*   offsets        = (int*)take((size_t)(N_NODES + 1) * 4);
    int*   cursor         = (int*)take((size_t)N_NODES * 4);
    int*   csr_src        = (int*)take((size_t)N_EDGES * 4);
    int*   bsums          = (int*)take((size_t)128 * 4);

    const int n = N_NODES, e = N_EDGES;
    const int nb = (n + 511) / 512;  // 98
    dim3 b256(256);

    k_init<<<dim3((n + 255) / 256), b256, 0, stream>>>(cursor, hg);
    k_h0_pack<<<dim3(12756), b256, 0, stream>>>(feat, W_in, b_in, h0, W_src, W_dst, Wpack);

    // CSR build
    k_hist<<<dim3((e + 255) / 256), b256, 0, stream>>>(dst, cursor, e);
    k_scan_local<<<dim3(nb), dim3(512), 0, stream>>>(cursor, offsets, bsums, n);
    k_scan_sums<<<dim3(1), dim3(128), 0, stream>>>(bsums, nb);
    k_scan_add<<<dim3(nb), dim3(512), 0, stream>>>(offsets, bsums, n);
    k_fill<<<dim3((e + 255) / 256), b256, 0, stream>>>(src, dst, offsets, cursor, csr_src, e);

    // 4 GATv2 layers
    const unsigned short* hin = h0;
    unsigned short* houts[4] = { hA, hB, hA, hB };
    for (int layer = 0; layer < 4; layer++) {
        k_gemm<<<dim3((n + 31) / 32, 2), b256, 0, stream>>>(hin, h0, Wpack, b_src, b_dst, fs, fd, n);
        k_agg<<<dim3((n + 3) / 4), b256, 0, stream>>>(fs, fd, offsets, csr_src, attn, houts[layer], n);
        hin = houts[layer];
    }

    // readout
    k_readout<<<dim3((n + 127) / 128), b256, 0, stream>>>(hB, is_root, gid, hg, n);
    k_out<<<dim3(1), dim3(512), 0, stream>>>(hg, W_out, b_out, out);
}

// Round 8
// 410.593 us; speedup vs baseline: 3.2459x; 1.1504x over previous
//
#include <hip/hip_runtime.h>
#include <math.h>

#define N_NODES 50000
#define N_EDGES 400000
#define N_GRAPHS 16
#define HEADS 4
#define NEG_SLOPE 0.2f

typedef __attribute__((ext_vector_type(8))) short short8;
typedef __attribute__((ext_vector_type(4))) float floatx4;
typedef _Float16 half_t;
typedef _Float16 half2_t __attribute__((ext_vector_type(2)));
typedef _Float16 half4_t __attribute__((ext_vector_type(4)));

__device__ __forceinline__ unsigned short f2bf(float x) {
    union { float f; unsigned int u; } v; v.f = x;
    unsigned int r = v.u + 0x7fffu + ((v.u >> 16) & 1u);
    return (unsigned short)(r >> 16);
}
__device__ __forceinline__ float bf2f(unsigned short b) {
    union { unsigned int u; float f; } v; v.u = ((unsigned int)b) << 16;
    return v.f;
}
__device__ __forceinline__ half2_t u2h2(unsigned int u) {
    union { unsigned int i; half2_t h; } v; v.i = u;
    return v.h;
}
__device__ __forceinline__ float fast_tanh(float x) {
    float e = __expf(2.f * x);
    return 1.f - 2.f / (e + 1.f);
}
__device__ __forceinline__ half2_t lrelu2(half2_t e) {
    half2_t s = e * (half2_t){(half_t)NEG_SLOPE, (half_t)NEG_SLOPE};
    return __builtin_elementwise_max(e, s);
}
__device__ __forceinline__ float dot2acc(half2_t a, half2_t b, float c) {
#if __has_builtin(__builtin_amdgcn_fdot2)
    return __builtin_amdgcn_fdot2(a, b, c, false);
#else
    return c + (float)a[0] * (float)b[0] + (float)a[1] * (float)b[1];
#endif
}

// ---------------- fused h0 + weight pack + zero cursor/hg ----------------
// blocks [0,12500): h0. [12500,12756): pack W. [12756,12952): zero cursor. 12952: zero hg.
__global__ __launch_bounds__(256) void k_h0_pack(const float* __restrict__ feat,
                                                 const float* __restrict__ W_in,
                                                 const float* __restrict__ b_in,
                                                 unsigned short* __restrict__ h0,
                                                 const float* __restrict__ Wsrc,
                                                 const float* __restrict__ Wdst,
                                                 unsigned short* __restrict__ Wpack,
                                                 int* __restrict__ cursor,
                                                 float* __restrict__ hg) {
    int bid = blockIdx.x;
    if (bid < 12500) {
        int idx = bid * 256 + threadIdx.x;
        int node = idx >> 6, d = idx & 63;
        float acc = b_in[d];
        #pragma unroll
        for (int k = 0; k < 16; k++) acc += feat[node * 16 + k] * W_in[k * 64 + d];
        h0[idx] = f2bf(acc);
    } else if (bid < 12756) {
        int pb = bid - 12500;                       // 0..255
        int mat = pb >> 7;                          // 0/1
        int idx = (pb & 127) * 256 + threadIdx.x;   // 0..32767
        const float* W = mat ? Wdst : Wsrc;
        int j = idx & 7;
        int lane = (idx >> 3) & 63;
        int q = (idx >> 9) & 3;
        int t = (idx >> 11) & 15;
        int col = t * 16 + (lane & 15);
        int k = q * 32 + (lane >> 4) * 8 + j;
        Wpack[mat * 32768 + idx] = f2bf(W[k * 256 + col]);
    } else if (bid < 12952) {
        int idx = (bid - 12756) * 256 + threadIdx.x;
        if (idx < N_NODES) cursor[idx] = 0;
    } else {
        for (int i = threadIdx.x; i < N_GRAPHS * 64; i += 256) hg[i] = 0.f;
    }
}

// ---------------- CSR build ----------------
__global__ __launch_bounds__(256) void k_hist(const int* __restrict__ dst, int* __restrict__ indeg, int e) {
    int i = blockIdx.x * 256 + threadIdx.x;
    if (i < e) atomicAdd(&indeg[dst[i]], 1);
}

__global__ __launch_bounds__(512) void k_scan_local(int* __restrict__ indeg,
                                                    int* __restrict__ offsets,
                                                    int* __restrict__ bsums, int n) {
    __shared__ int tmp[512];
    int t = threadIdx.x;
    int idx = blockIdx.x * 512 + t;
    int v = (idx < n) ? indeg[idx] : 0;
    tmp[t] = v;
    __syncthreads();
    #pragma unroll
    for (int off = 1; off < 512; off <<= 1) {
        int add = (t >= off) ? tmp[t - off] : 0;
        __syncthreads();
        tmp[t] += add;
        __syncthreads();
    }
    if (idx < n) { offsets[idx] = tmp[t] - v; indeg[idx] = 0; }
    if (t == 511) bsums[blockIdx.x] = tmp[511];
}

// scan_add with self-computed prefix over raw bsums (<=512 entries)
__global__ __launch_bounds__(512) void k_scan_add(int* __restrict__ offsets,
                                                  const int* __restrict__ bsums,
                                                  int nb, int n) {
    __shared__ int red[512];
    int t = threadIdx.x;
    int b = blockIdx.x;
    red[t] = (t < nb && t < b) ? bsums[t] : 0;
    __syncthreads();
    #pragma unroll
    for (int s = 256; s >= 1; s >>= 1) {
        if (t < s) red[t] += red[t + s];
        __syncthreads();
    }
    int prefix = red[0];
    int idx = b * 512 + t;
    if (idx < n) offsets[idx] += prefix;
    if (b == 0 && t == 0) offsets[n] = N_EDGES;
}

__global__ __launch_bounds__(256) void k_fill(const int* __restrict__ src, const int* __restrict__ dst,
                                              const int* __restrict__ offsets, int* __restrict__ cursor,
                                              int* __restrict__ csr_src, int e) {
    int i = blockIdx.x * 256 + threadIdx.x;
    if (i >= e) return;
    int d = dst[i];
    int slot = offsets[d] + atomicAdd(&cursor[d], 1);
    csr_src[slot] = src[i];
}

// ---------------- fs/fd = [h|h0] @ W + b  via MFMA, LDS-staged coalesced stores ----------------
// wave = 16 nodes x 128 feats. Block 256 = 4 waves = 32 nodes x 256 feats.
// grid.x = ceil(n/32), grid.y = 2 (mat)
__global__ __launch_bounds__(256) void k_gemm(const unsigned short* __restrict__ h,
                                              const unsigned short* __restrict__ h0,
                                              const unsigned short* __restrict__ Wpack,
                                              const float* __restrict__ bsrc,
                                              const float* __restrict__ bdst,
                                              half_t* __restrict__ fs,
                                              half_t* __restrict__ fd, int n) {
    __shared__ half_t tile[32][264];   // row pad +8 halfs -> 2-way bank aliasing (free)
    int mat = blockIdx.y;
    const unsigned short* Wp = Wpack + mat * 32768;
    const float* bias = mat ? bdst : bsrc;
    half_t* out = mat ? fd : fs;
    int wave = threadIdx.x >> 6, lane = threadIdx.x & 63;
    int quad = lane >> 4, m16 = lane & 15;
    int fhalf = wave & 1;
    int ngrp = wave >> 1;
    int node0 = blockIdx.x * 32 + ngrp * 16;

    floatx4 acc[8];
    #pragma unroll
    for (int t = 0; t < 8; t++) acc[t] = (floatx4){0.f, 0.f, 0.f, 0.f};

    int r = node0 + m16;
    if (r > n - 1) r = n - 1;

    #pragma unroll
    for (int q = 0; q < 4; q++) {
        int kk = q * 32 + quad * 8;
        const unsigned short* base = (kk < 64) ? (h + (size_t)r * 64 + kk)
                                               : (h0 + (size_t)r * 64 + (kk - 64));
        short8 x = *(const short8*)base;
        #pragma unroll
        for (int t = 0; t < 8; t++) {
            int tt = fhalf * 8 + t;
            short8 w = *(const short8*)(Wp + ((size_t)(tt * 4 + q) * 64 + lane) * 8);
            acc[t] = __builtin_amdgcn_mfma_f32_16x16x32_bf16(w, x, acc[t], 0, 0, 0);
        }
    }
    // epilogue: bias + cvt f16 -> LDS tile
    int lrow = ngrp * 16 + m16;
    #pragma unroll
    for (int t = 0; t < 8; t++) {
        int fbase = (fhalf * 8 + t) * 16 + quad * 4;
        float4 bb = *(const float4*)(bias + fbase);
        half4_t ov = { (half_t)(acc[t][0] + bb.x), (half_t)(acc[t][1] + bb.y),
                       (half_t)(acc[t][2] + bb.z), (half_t)(acc[t][3] + bb.w) };
        *(half4_t*)&tile[lrow][fbase] = ov;
    }
    __syncthreads();
    // coalesced store: 32 rows x 512 B, 16 B per thread-iter
    int base = blockIdx.x * 32;
    for (int i = threadIdx.x; i < 1024; i += 256) {
        int row = i >> 5, seg = i & 31;
        int node = base + row;
        if (node < n) {
            uint4 v = *(const uint4*)&tile[row][seg * 8];
            *(uint4*)(out + (size_t)node * 256 + seg * 8) = v;
        }
    }
}

// ---------------- per-node aggregation: packed-f16, slot-split epilogue ----------------
// lane = (slot = lane>>5, head = (lane>>3)&3, dg = lane&7 -> dims dg*8..+7)
__global__ __launch_bounds__(256) void k_agg(const half_t* __restrict__ fs,
                                             const half_t* __restrict__ fd,
                                             const int* __restrict__ offsets,
                                             const int* __restrict__ csr_src,
                                             const float* __restrict__ attn,
                                             unsigned short* __restrict__ hout, int n) {
    int wave = threadIdx.x >> 6;
    int lane = threadIdx.x & 63;
    int node = blockIdx.x * 4 + wave;
    if (node >= n) return;
    int slot = lane >> 5;
    int foff = ((lane >> 3) & 3) * 64 + (lane & 7) * 8;   // head*64 + dg*8
    unsigned boff = (unsigned)foff * 2;                   // byte offset in f16 row
    const char* fsb = (const char*)fs;

    half2_t at2[4];
    {
        float4 a0 = *(const float4*)(attn + foff);
        float4 a1 = *(const float4*)(attn + foff + 4);
        at2[0] = (half2_t){(half_t)a0.x, (half_t)a0.y};
        at2[1] = (half2_t){(half_t)a0.z, (half_t)a0.w};
        at2[2] = (half2_t){(half_t)a1.x, (half_t)a1.y};
        at2[3] = (half2_t){(half_t)a1.z, (half_t)a1.w};
    }
    half2_t fd2[4];
    {
        uint4 u = *(const uint4*)(fd + (size_t)node * 256 + foff);
        fd2[0] = u2h2(u.x); fd2[1] = u2h2(u.y); fd2[2] = u2h2(u.z); fd2[3] = u2h2(u.w);
    }

    float l = 0.f;
    half2_t zero2 = {(half_t)0.f, (half_t)0.f};
    half2_t acc2[4] = {zero2, zero2, zero2, zero2};

    int beg = offsets[node], end = offsets[node + 1];
    for (int j = beg; j < end; j += 4) {
        int e0 = j + slot, e1 = j + 2 + slot;
        bool v0 = e0 < end, v1 = e1 < end;
        int s0 = csr_src[v0 ? e0 : beg];
        int s1 = csr_src[v1 ? e1 : beg];
        uint4 g0 = *(const uint4*)(fsb + (((unsigned)s0 << 9) + boff));
        uint4 g1 = *(const uint4*)(fsb + (((unsigned)s1 << 9) + boff));
        half2_t f0[4] = {u2h2(g0.x), u2h2(g0.y), u2h2(g0.z), u2h2(g0.w)};
        half2_t f1[4] = {u2h2(g1.x), u2h2(g1.y), u2h2(g1.z), u2h2(g1.w)};
        float p0 = 0.f, p1 = 0.f;
        #pragma unroll
        for (int k = 0; k < 4; k++) {
            p0 = dot2acc(at2[k], lrelu2(f0[k] + fd2[k]), p0);
            p1 = dot2acc(at2[k], lrelu2(f1[k] + fd2[k]), p1);
        }
        p0 += __shfl_xor(p0, 1, 64); p1 += __shfl_xor(p1, 1, 64);
        p0 += __shfl_xor(p0, 2, 64); p1 += __shfl_xor(p1, 2, 64);
        p0 += __shfl_xor(p0, 4, 64); p1 += __shfl_xor(p1, 4, 64);
        float w0 = v0 ? __expf(fminf(p0, 80.f)) : 0.f;
        float w1 = v1 ? __expf(fminf(p1, 80.f)) : 0.f;
        l += w0 + w1;
        half_t hw0 = (half_t)w0, hw1 = (half_t)w1;
        half2_t w02 = {hw0, hw0}, w12 = {hw1, hw1};
        #pragma unroll
        for (int k = 0; k < 4; k++) {
            acc2[k] += w02 * f0[k];
            acc2[k] += w12 * f1[k];
        }
    }
    // merge the two edge-slots (xor 32)
    l += __shfl_xor(l, 32, 64);
    #pragma unroll
    for (int k = 0; k < 4; k++) {
        float t = __builtin_bit_cast(float, acc2[k]);
        t = __shfl_xor(t, 32, 64);
        acc2[k] += __builtin_bit_cast(half2_t, t);
    }

    float inv = (l > 0.f) ? 1.f / l : 0.f;
    // slot-split epilogue: slot 0 -> dims dg*8..+3, slot 1 -> dims dg*8+4..+7
    half2_t a0 = slot ? acc2[2] : acc2[0];
    half2_t a1 = slot ? acc2[3] : acc2[1];
    float o0 = fast_tanh((float)a0[0] * inv);
    float o1 = fast_tanh((float)a0[1] * inv);
    float o2 = fast_tanh((float)a1[0] * inv);
    float o3 = fast_tanh((float)a1[1] * inv);
    // head sum within each 32-lane half (lane bits 3,4)
    o0 += __shfl_xor(o0, 8, 64);  o0 += __shfl_xor(o0, 16, 64);
    o1 += __shfl_xor(o1, 8, 64);  o1 += __shfl_xor(o1, 16, 64);
    o2 += __shfl_xor(o2, 8, 64);  o2 += __shfl_xor(o2, 16, 64);
    o3 += __shfl_xor(o3, 8, 64);  o3 += __shfl_xor(o3, 16, 64);
    if ((lane & 31) < 8) {
        ushort4 ov = {f2bf(o0), f2bf(o1), f2bf(o2), f2bf(o3)};
        *(ushort4*)(hout + (size_t)node * 64 + (lane & 7) * 8 + slot * 4) = ov;
    }
}

// ---------------- graph readout: wave per 32 nodes, register accumulate ----------------
__global__ __launch_bounds__(256) void k_readout(const unsigned short* __restrict__ h,
                                                 const float* __restrict__ is_root,
                                                 const int* __restrict__ gid, float* __restrict__ hg, int n) {
    int wave = threadIdx.x >> 6, lane = threadIdx.x & 63;
    int start = blockIdx.x * 128 + wave * 32;
    if (start >= n) return;
    int stop = min(start + 32, n);
    float acc = 0.f;
    int cur = gid[start];
    for (int i = start; i < stop; i++) {
        int g = gid[i];
        if (g != cur) {
            atomicAdd(&hg[cur * 64 + lane], acc);
            acc = 0.f;
            cur = g;
        }
        acc += bf2f(h[(size_t)i * 64 + lane]) * is_root[i];
    }
    atomicAdd(&hg[cur * 64 + lane], acc);
}

__global__ __launch_bounds__(512) void k_out(const float* __restrict__ hg, const float* __restrict__ W_out,
                                             const float* __restrict__ b_out, float* __restrict__ out) {
    int t = threadIdx.x;
    if (t >= N_GRAPHS * 32) return;
    int b = t >> 5, c = t & 31;
    float a = b_out[c];
    #pragma unroll
    for (int d = 0; d < 64; d++) a += hg[b * 64 + d] * W_out[d * 32 + c];
    out[t] = a;
}

extern "C" void kernel_launch(void* const* d_in, const int* in_sizes, int n_in,
                              void* d_out, int out_size, void* d_ws, size_t ws_size,
                              hipStream_t stream) {
    const float* feat    = (const float*)d_in[0];
    const float* is_root = (const float*)d_in[1];
    const int*   src     = (const int*)d_in[2];
    const int*   dst     = (const int*)d_in[3];
    const int*   gid     = (const int*)d_in[4];
    const float* W_in    = (const float*)d_in[5];
    const float* b_in    = (const float*)d_in[6];
    const float* W_src   = (const float*)d_in[7];
    const float* b_src   = (const float*)d_in[8];
    const float* W_dst   = (const float*)d_in[9];
    const float* b_dst   = (const float*)d_in[10];
    const float* attn    = (const float*)d_in[11];
    const float* W_out   = (const float*)d_in[12];
    const float* b_out   = (const float*)d_in[13];
    float* out = (float*)d_out;

    char* ws = (char*)d_ws;
    size_t off = 0;
    auto take = [&](size_t bytes) -> char* {
        char* p = ws + off;
        off = (off + bytes + 255) & ~(size_t)255;
        return p;
    };
    half_t* fs            = (half_t*)take((size_t)N_NODES * 256 * 2);
    half_t* fd            = (half_t*)take((size_t)N_NODES * 256 * 2);
    unsigned short* h0    = (unsigned short*)take((size_t)N_NODES * 64 * 2);
    unsigned short* hA    = (unsigned short*)take((size_t)N_NODES * 64 * 2);
    unsigned short* hB    = (unsigned short*)take((size_t)N_NODES * 64 * 2);
    unsigned short* Wpack = (unsigned short*)take((size_t)2 * 32768 * 2);
    float* hg             = (float*)take((size_t)N_GRAPHS * 64 * 4);
    int*   offsets        = (int*)take((size_t)(N_NODES + 1) * 4);
    int*   cursor         = (int*)take((size_t)N_NODES * 4);
    int*   csr_src        = (int*)take((size_t)N_EDGES * 4);
    int*   bsums          = (int*)take((size_t)512 * 4);

    const int n = N_NODES, e = N_EDGES;
    const int nb = (n + 511) / 512;  // 98
    dim3 b256(256);

    k_h0_pack<<<dim3(12953), b256, 0, stream>>>(feat, W_in, b_in, h0, W_src, W_dst, Wpack, cursor, hg);

    // CSR build
    k_hist<<<dim3((e + 255) / 256), b256, 0, stream>>>(dst, cursor, e);
    k_scan_local<<<dim3(nb), dim3(512), 0, stream>>>(cursor, offsets, bsums, n);
    k_scan_add<<<dim3(nb), dim3(512), 0, stream>>>(offsets, bsums, nb, n);
    k_fill<<<dim3((e + 255) / 256), b256, 0, stream>>>(src, dst, offsets, cursor, csr_src, e);

    // 4 GATv2 layers
    const unsigned short* hin = h0;
    unsigned short* houts[4] = { hA, hB, hA, hB };
    for (int layer = 0; layer < 4; layer++) {
        k_gemm<<<dim3((n + 31) / 32, 2), b256, 0, stream>>>(hin, h0, Wpack, b_src, b_dst, fs, fd, n);
        k_agg<<<dim3((n + 3) / 4), b256, 0, stream>>>(fs, fd, offsets, csr_src, attn, houts[layer], n);
        hin = houts[layer];
    }

    // readout
    k_readout<<<dim3((n + 127) / 128), b256, 0, stream>>>(hB, is_root, gid, hg, n);
    k_out<<<dim3(1), dim3(512), 0, stream>>>(hg, W_out, b_out, out);
}